// Round 4
// baseline (627.136 us; speedup 1.0000x reference)
//
#include <hip/hip_runtime.h>
#include <hip/hip_bf16.h>

// Problem constants (compile-time; n_heads input d_in[9] ignored).
// Inputs/outputs FLOAT32 (per reference). Intermediates fp16 in d_ws.
// R9 (bisect): proj reverted to the R6-PROVEN fp32 VALU kernel, with the
//     single change packbf->packh (KpT/VpT now f16). wt_convert/proj_mfma
//     removed. attn stays f16, out_gemm stays f16 (proven in R6 form).
//     Isolates R7/R8's failure to {wt_convert,proj_mfma} vs attn-f16.
#define BB      4
#define SEQ     4096
#define DMODEL  1024
#define NHEAD   16
#define DK      64
#define LK      256
#define BH      (BB*NHEAD)   // 64

typedef unsigned short u16;
typedef unsigned int   u32;
typedef float f32x4  __attribute__((ext_vector_type(4)));
typedef _Float16 f16x8 __attribute__((ext_vector_type(8)));

__device__ __forceinline__ u16 f2h(float f) {
    _Float16 h = (_Float16)f;                 // v_cvt_f16_f32, RNE
    u16 r; __builtin_memcpy(&r, &h, 2); return r;
}
__device__ __forceinline__ u32 packh(float a, float b) {
    return (u32)f2h(a) | ((u32)f2h(b) << 16);
}
// async global->LDS, 16B per lane (dest must be wave-uniform base + lane*16)
__device__ __forceinline__ void gl2lds16(const void* g, void* l) {
    __builtin_amdgcn_global_load_lds(
        (const __attribute__((address_space(1))) unsigned int*)g,
        (__attribute__((address_space(3))) unsigned int*)l,
        16, 0, 0);
}

// ---------------------------------------------------------------------------
// Kernel 1: projections (R6-proven fp32 VALU version; epilogue packs f16).
// z=0: KpT[bh][LK][DK] = sum_n We[n,k]*K[b,n,h*64+d] + be[k]   (d contiguous)
// z=1: VpT[bh][DK][LK] = sum_n Wf[n,k]*V[b,n,h*64+d] + bf[k]   (k contiguous!)
// ---------------------------------------------------------------------------
__global__ __launch_bounds__(256) void proj_kernel(
    const float* __restrict__ Kin, const float* __restrict__ Vin,
    const float* __restrict__ We,  const float* __restrict__ be,
    const float* __restrict__ Wf,  const float* __restrict__ bfp,
    u16* __restrict__ KpT, u16* __restrict__ VpT)
{
    const int kq = blockIdx.x;            // k0 = kq*64
    const int bh = blockIdx.y;
    const int b  = bh >> 4, h = bh & 15;
    const int isV = blockIdx.z;
    const float* Inp  = isV ? Vin : Kin;
    const float* W    = isV ? Wf  : We;
    const float* bias = isV ? bfp : be;
    u16* Out          = isV ? VpT : KpT;

    __shared__ float Wl[64][68];          // [nn][k_local]
    __shared__ float Il[64][68];          // [nn][d]

    const int t  = threadIdx.x;
    const int k0 = kq * 64;
    const int kg = t >> 4;                // k_local = kg*4
    const int dg = t & 15;                // d = dg*4

    float acc[4][4];
#pragma unroll
    for (int i = 0; i < 4; ++i)
#pragma unroll
        for (int j = 0; j < 4; ++j) acc[i][j] = 0.f;

    for (int n0 = 0; n0 < SEQ; n0 += 64) {
        __syncthreads();
#pragma unroll
        for (int pass = 0; pass < 2; ++pass) {
            int idx = t + pass * 256;
            int nn  = idx >> 3;
            int c8  = (idx & 7) * 8;
            const float* wsrc = W + (size_t)(n0 + nn) * LK + k0 + c8;
            *(float4*)&Wl[nn][c8]     = *(const float4*)(wsrc);
            *(float4*)&Wl[nn][c8 + 4] = *(const float4*)(wsrc + 4);
            const float* isrc = Inp + ((size_t)b * SEQ + n0 + nn) * DMODEL + h * DK + c8;
            *(float4*)&Il[nn][c8]     = *(const float4*)(isrc);
            *(float4*)&Il[nn][c8 + 4] = *(const float4*)(isrc + 4);
        }
        __syncthreads();
#pragma unroll 8
        for (int nn = 0; nn < 64; ++nn) {
            const float4 w4 = *(const float4*)&Wl[nn][kg * 4];
            const float4 i4 = *(const float4*)&Il[nn][dg * 4];
            acc[0][0] += w4.x * i4.x; acc[0][1] += w4.x * i4.y; acc[0][2] += w4.x * i4.z; acc[0][3] += w4.x * i4.w;
            acc[1][0] += w4.y * i4.x; acc[1][1] += w4.y * i4.y; acc[1][2] += w4.y * i4.z; acc[1][3] += w4.y * i4.w;
            acc[2][0] += w4.z * i4.x; acc[2][1] += w4.z * i4.y; acc[2][2] += w4.z * i4.z; acc[2][3] += w4.z * i4.w;
            acc[3][0] += w4.w * i4.x; acc[3][1] += w4.w * i4.y; acc[3][2] += w4.w * i4.z; acc[3][3] += w4.w * i4.w;
        }
    }

    if (!isV) {
        // KpT[bh][k][d]: pack 4 d for each of 4 k
#pragma unroll
        for (int i = 0; i < 4; ++i) {
            int k = k0 + kg * 4 + i;
            float bv = bias[k];
            uint2 o = make_uint2(packh(acc[i][0] + bv, acc[i][1] + bv),
                                 packh(acc[i][2] + bv, acc[i][3] + bv));
            *(uint2*)(Out + ((size_t)bh * LK + k) * DK + dg * 4) = o;
        }
    } else {
        // VpT[bh][d][k]: pack 4 consecutive k for each of 4 d (bias varies with k)
        float bv0 = bias[k0 + kg * 4 + 0], bv1 = bias[k0 + kg * 4 + 1];
        float bv2 = bias[k0 + kg * 4 + 2], bv3 = bias[k0 + kg * 4 + 3];
#pragma unroll
        for (int j = 0; j < 4; ++j) {
            int d = dg * 4 + j;
            uint2 o = make_uint2(packh(acc[0][j] + bv0, acc[1][j] + bv1),
                                 packh(acc[2][j] + bv2, acc[3][j] + bv3));
            *(uint2*)(Out + ((size_t)bh * DK + d) * LK + k0 + kg * 4) = o;
        }
    }
}

// ---------------------------------------------------------------------------
// Kernel 2 (MFMA, f16): fused scores+softmax+PV. Block = 64 Q-rows x (b,h),
// 4 waves, wave w owns rows w*16..w*16+15 end-to-end.
// A layout: A[m=lane&15][k=quad*8+j]; B: B[n=lane&15][k=quad*8+j];
// C/D: col=lane&15, row=quad*4+reg.
// ---------------------------------------------------------------------------
__global__ __launch_bounds__(256) void attn_mfma(
    const float* __restrict__ Qin, const u16* __restrict__ KpT,
    const u16* __restrict__ VpT,   u16* __restrict__ AO)
{
    const int bh = blockIdx.y, b = bh >> 4, h = bh & 15;
    const int n0 = blockIdx.x * 64;
    const int t  = threadIdx.x;
    const int w    = t >> 6;          // wave 0..3
    const int lane = t & 63;
    const int q    = lane >> 4;       // quad 0..3
    const int c    = lane & 15;

    __shared__ u16 Qs[64][72];        // Q tile f16 (+8 pad)
    __shared__ u16 Pl[64][264];       // P tile f16 (+8 pad)

    // ---- stage Q (fp32 -> f16), wave w stages its own 16 rows ----
    {
        int lr = lane >> 2, col0 = (lane & 3) * 16;
        const float* src = Qin + ((size_t)b * SEQ + n0 + w * 16 + lr) * DMODEL + h * DK + col0;
        float4 f0 = ((const float4*)src)[0];
        float4 f1 = ((const float4*)src)[1];
        float4 f2 = ((const float4*)src)[2];
        float4 f3 = ((const float4*)src)[3];
        uint4 p0, p1;
        p0.x = packh(f0.x, f0.y); p0.y = packh(f0.z, f0.w);
        p0.z = packh(f1.x, f1.y); p0.w = packh(f1.z, f1.w);
        p1.x = packh(f2.x, f2.y); p1.y = packh(f2.z, f2.w);
        p1.z = packh(f3.x, f3.y); p1.w = packh(f3.z, f3.w);
        *(uint4*)&Qs[w * 16 + lr][col0]     = p0;
        *(uint4*)&Qs[w * 16 + lr][col0 + 8] = p1;
    }
    __syncthreads();

    // ---- A-fragments for QK^T (row m = w*16 + c, k = d) ----
    f16x8 a0 = *(const f16x8*)&Qs[w * 16 + c][q * 8];
    f16x8 a1 = *(const f16x8*)&Qs[w * 16 + c][32 + q * 8];

    // ---- scores: 16 col-tiles of 16 lk each; B-frags straight from L2 ----
    f32x4 sc[16];
#pragma unroll
    for (int nt = 0; nt < 16; ++nt) sc[nt] = (f32x4){0.f, 0.f, 0.f, 0.f};

    const u16* kb = KpT + (size_t)bh * LK * DK;
#pragma unroll
    for (int nt = 0; nt < 16; ++nt) {
        const u16* kp = kb + (size_t)(nt * 16 + c) * DK + q * 8;
        f16x8 b0 = *(const f16x8*)(kp);
        f16x8 b1 = *(const f16x8*)(kp + 32);
        sc[nt] = __builtin_amdgcn_mfma_f32_16x16x32_f16(a0, b0, sc[nt], 0, 0, 0);
        sc[nt] = __builtin_amdgcn_mfma_f32_16x16x32_f16(a1, b1, sc[nt], 0, 0, 0);
    }

    // ---- softmax over 256 cols, entirely in registers ----
    float mx[4] = {-1e30f, -1e30f, -1e30f, -1e30f};
#pragma unroll
    for (int nt = 0; nt < 16; ++nt) {
        sc[nt] *= 0.125f;   // 1/sqrt(DK)
#pragma unroll
        for (int r = 0; r < 4; ++r) mx[r] = fmaxf(mx[r], sc[nt][r]);
    }
#pragma unroll
    for (int d = 1; d < 16; d <<= 1)
#pragma unroll
        for (int r = 0; r < 4; ++r) mx[r] = fmaxf(mx[r], __shfl_xor(mx[r], d, 64));

    float sm[4] = {0.f, 0.f, 0.f, 0.f};
#pragma unroll
    for (int nt = 0; nt < 16; ++nt)
#pragma unroll
        for (int r = 0; r < 4; ++r) {
            float e = __expf(sc[nt][r] - mx[r]);
            sc[nt][r] = e;
            sm[r] += e;
        }
#pragma unroll
    for (int d = 1; d < 16; d <<= 1)
#pragma unroll
        for (int r = 0; r < 4; ++r) sm[r] += __shfl_xor(sm[r], d, 64);
    float inv[4];
#pragma unroll
    for (int r = 0; r < 4; ++r) inv[r] = 1.0f / sm[r];

    // ---- P: C-layout regs -> LDS (row-major f16) for A-operand re-read ----
#pragma unroll
    for (int nt = 0; nt < 16; ++nt)
#pragma unroll
        for (int r = 0; r < 4; ++r)
            Pl[w * 16 + q * 4 + r][nt * 16 + c] = f2h(sc[nt][r] * inv[r]);

    // ---- PV: out[16 x 64] per wave; A from LDS, B from VpT (L2) ----
    f32x4 ov[4];
#pragma unroll
    for (int nt = 0; nt < 4; ++nt) ov[nt] = (f32x4){0.f, 0.f, 0.f, 0.f};
    const u16* vb = VpT + (size_t)bh * DK * LK;
#pragma unroll
    for (int ks = 0; ks < 8; ++ks) {
        f16x8 pa = *(const f16x8*)&Pl[w * 16 + c][ks * 32 + q * 8];
#pragma unroll
        for (int nt = 0; nt < 4; ++nt) {
            f16x8 vf = *(const f16x8*)(vb + (size_t)(nt * 16 + c) * LK + ks * 32 + q * 8);
            ov[nt] = __builtin_amdgcn_mfma_f32_16x16x32_f16(pa, vf, ov[nt], 0, 0, 0);
        }
    }

    // ---- stage out tile into reused Qs (f16), then coalesced 16B stores ----
#pragma unroll
    for (int nt = 0; nt < 4; ++nt)
#pragma unroll
        for (int r = 0; r < 4; ++r)
            Qs[w * 16 + q * 4 + r][nt * 16 + c] = f2h(ov[nt][r]);

#pragma unroll
    for (int pass = 0; pass < 2; ++pass) {
        int lr  = w * 16 + pass * 8 + (lane >> 3);
        int col = (lane & 7) * 8;
        uint4 vv = *(uint4*)&Qs[lr][col];
        *(uint4*)(AO + ((size_t)b * SEQ + n0 + lr) * DMODEL + h * DK + col) = vv;
    }
}

// ---------------------------------------------------------------------------
// Kernel 3a: WoT[j][k] fp16 = Wo[k][j] f32.  (R6-proven)
// ---------------------------------------------------------------------------
__global__ __launch_bounds__(256) void wo_convert(
    const float* __restrict__ Wo, u16* __restrict__ WoT)
{
    const int n0 = blockIdx.x * 64, k0 = blockIdx.y * 64;
    __shared__ float T[64][65];
    const int t = threadIdx.x;
    {
        int kr = (t >> 4) * 4;
        int nc = (t & 15) * 4;
#pragma unroll
        for (int i = 0; i < 4; ++i) {
            float4 v = *(const float4*)(Wo + (size_t)(k0 + kr + i) * DMODEL + n0 + nc);
            T[kr + i][nc + 0] = v.x; T[kr + i][nc + 1] = v.y;
            T[kr + i][nc + 2] = v.z; T[kr + i][nc + 3] = v.w;
        }
    }
    __syncthreads();
    int n = t >> 2, kc = (t & 3) * 16;
    u32 o[8];
#pragma unroll
    for (int j = 0; j < 8; ++j)
        o[j] = packh(T[kc + j * 2][n], T[kc + j * 2 + 1][n]);
    u16* dst = WoT + (size_t)(n0 + n) * DMODEL + k0 + kc;
    *(uint4*)(dst)     = make_uint4(o[0], o[1], o[2], o[3]);
    *(uint4*)(dst + 8) = make_uint4(o[4], o[5], o[6], o[7]);
}

// ---------------------------------------------------------------------------
// Kernel 3 (MFMA, R6-proven): Out[16384][1024] = AO(f16) @ WoT^T(f16) + bo.
// 128x128 tile, BK=64, 4 waves 2x2, f16 16x16x32, gl2lds w16 + T2 swizzle.
// ---------------------------------------------------------------------------
#define OBM 128
#define OBN 128
#define OBK 64

__global__ __launch_bounds__(256) void out_gemm_mfma(
    const u16* __restrict__ AO, const u16* __restrict__ WoT,
    const float* __restrict__ bo, float* __restrict__ Out)
{
    const int c0 = blockIdx.x * OBN;
    const int r0 = blockIdx.y * OBM;
    const int t  = threadIdx.x;
    const int lane = t & 63;
    const int w  = t >> 6;
    const int wr = w >> 1, wc = w & 1;     // 2x2 wave grid, 64x64 each
    const int q  = lane >> 4, c = lane & 15;

    __shared__ u16 As[OBM * OBK];   // 16 KB, swizzled storage
    __shared__ u16 Bs[OBN * OBK];   // 16 KB

    f32x4 acc[4][4];
#pragma unroll
    for (int m = 0; m < 4; ++m)
#pragma unroll
        for (int n = 0; n < 4; ++n) acc[m][n] = (f32x4){0.f, 0.f, 0.f, 0.f};

    for (int k0 = 0; k0 < DMODEL; k0 += OBK) {
#pragma unroll
        for (int i = 0; i < 4; ++i) {
            int li  = i * 256 + t;
            int row = li >> 3;
            int c8  = (li & 7) ^ (row & 7);
            gl2lds16(AO  + (size_t)(r0 + row) * DMODEL + k0 + c8 * 8, (u16*)As + (size_t)li * 8);
            gl2lds16(WoT + (size_t)(c0 + row) * DMODEL + k0 + c8 * 8, (u16*)Bs + (size_t)li * 8);
        }
        __syncthreads();

#pragma unroll
        for (int s = 0; s < 2; ++s) {
            f16x8 af[4], bf[4];
#pragma unroll
            for (int m = 0; m < 4; ++m) {
                int row = wr * 64 + m * 16 + c;
                int c8  = (s * 4 + q) ^ (row & 7);
                af[m] = *(const f16x8*)&As[row * 64 + c8 * 8];
            }
#pragma unroll
            for (int n = 0; n < 4; ++n) {
                int row = wc * 64 + n * 16 + c;
                int c8  = (s * 4 + q) ^ (row & 7);
                bf[n] = *(const f16x8*)&Bs[row * 64 + c8 * 8];
            }
#pragma unroll
            for (int m = 0; m < 4; ++m)
#pragma unroll
                for (int n = 0; n < 4; ++n)
                    acc[m][n] = __builtin_amdgcn_mfma_f32_16x16x32_f16(af[m], bf[n], acc[m][n], 0, 0, 0);
        }
        __syncthreads();
    }

    float bv[4];
#pragma unroll
    for (int n = 0; n < 4; ++n) bv[n] = bo[c0 + wc * 64 + n * 16 + c];
#pragma unroll
    for (int m = 0; m < 4; ++m) {
        int rowb = r0 + wr * 64 + m * 16 + q * 4;
#pragma unroll
        for (int r = 0; r < 4; ++r) {
            float* dst = Out + (size_t)(rowb + r) * DMODEL + c0 + wc * 64 + c;
#pragma unroll
            for (int n = 0; n < 4; ++n) dst[n * 16] = acc[m][n][r] + bv[n];
        }
    }
}

// ---------------------------------------------------------------------------
extern "C" void kernel_launch(void* const* d_in, const int* in_sizes, int n_in,
                              void* d_out, int out_size, void* d_ws, size_t ws_size,
                              hipStream_t stream)
{
    const float* K   = (const float*)d_in[0];
    const float* Q   = (const float*)d_in[1];
    const float* V   = (const float*)d_in[2];
    const float* We  = (const float*)d_in[3];
    const float* be  = (const float*)d_in[4];
    const float* Wf  = (const float*)d_in[5];
    const float* bfp = (const float*)d_in[6];
    const float* Wo  = (const float*)d_in[7];
    const float* bo  = (const float*)d_in[8];
    float* Out = (float*)d_out;

    // ws (f16), total 39.5MB (exact R6-proven layout):
    //   KpT 2MB | VpT 2MB | AO 33.5MB | WoT 2MB
    u16* KpT = (u16*)d_ws;
    u16* VpT = KpT + (size_t)BH * LK * DK;
    u16* AO  = VpT + (size_t)BH * LK * DK;
    u16* WoT = AO  + (size_t)BB * SEQ * DMODEL;

    wo_convert<<<dim3(DMODEL / 64, DMODEL / 64), 256, 0, stream>>>(Wo, WoT);
    proj_kernel<<<dim3(4, 64, 2), 256, 0, stream>>>(K, V, We, be, Wf, bfp, KpT, VpT);
    attn_mfma<<<dim3(SEQ / 64, BH), 256, 0, stream>>>(Q, KpT, VpT, AO);
    out_gemm_mfma<<<dim3(DMODEL / OBN, (BB * SEQ) / OBM), 256, 0, stream>>>(AO, WoT, bo, Out);
}

// Round 5
// 545.773 us; speedup vs baseline: 1.1491x; 1.1491x over previous
//
#include <hip/hip_runtime.h>
#include <hip/hip_bf16.h>

// Problem constants (compile-time; n_heads input d_in[9] ignored).
// Inputs/outputs FLOAT32 (per reference). Intermediates fp16 in d_ws.
// R10: projection rebuilt from PROVEN pieces only:
//  - tconv = wo_convert body with stride args (f32->f16 transpose)
//  - proj_gemm = out_gemm_mfma body (128x128, BK=64, swizzle+gl2lds) with
//    KLEN=4096, batch ptrs, bias on row (K-proj) or col (V-proj), f16 out.
//  Per-b full-model GEMMs: KpFull[b][k][dm]=WeT@KT[b]; VpFull[b][dm][k]=VT[b]@WfT.
//  attn reads KpFull (stride DMODEL) / VpFull (stride LK) via 2-line patch.
//  ws stays EXACTLY 39.5MB (R6-proven) via serial aliasing.
#define BB      4
#define SEQ     4096
#define DMODEL  1024
#define NHEAD   16
#define DK      64
#define LK      256
#define BH      (BB*NHEAD)   // 64

typedef unsigned short u16;
typedef unsigned int   u32;
typedef float f32x4  __attribute__((ext_vector_type(4)));
typedef _Float16 f16x8 __attribute__((ext_vector_type(8)));

__device__ __forceinline__ u16 f2h(float f) {
    _Float16 h = (_Float16)f;                 // v_cvt_f16_f32, RNE
    u16 r; __builtin_memcpy(&r, &h, 2); return r;
}
__device__ __forceinline__ u32 packh(float a, float b) {
    return (u32)f2h(a) | ((u32)f2h(b) << 16);
}
// async global->LDS, 16B per lane (dest must be wave-uniform base + lane*16)
__device__ __forceinline__ void gl2lds16(const void* g, void* l) {
    __builtin_amdgcn_global_load_lds(
        (const __attribute__((address_space(1))) unsigned int*)g,
        (__attribute__((address_space(3))) unsigned int*)l,
        16, 0, 0);
}

// ---------------------------------------------------------------------------
// Kernel 0: generic transpose+convert, f32 [R][C] -> f16 [C][R].
// Body == proven wo_convert; strides/batch offsets as args.
// grid (R/64, C/64, batch). ss=src row stride, ds=dst row stride.
// ---------------------------------------------------------------------------
__global__ __launch_bounds__(256) void tconv(
    const float* __restrict__ src, u16* __restrict__ dst,
    int ss, int ds, size_t sbo, size_t dbo)
{
    const float* S = src + (size_t)blockIdx.z * sbo;
    u16* D         = dst + (size_t)blockIdx.z * dbo;
    const int r0 = blockIdx.x * 64;   // src rows
    const int c0 = blockIdx.y * 64;   // src cols
    __shared__ float T[64][65];
    const int t = threadIdx.x;
    {
        int rr = (t >> 4) * 4;
        int cc = (t & 15) * 4;
#pragma unroll
        for (int i = 0; i < 4; ++i) {
            float4 v = *(const float4*)(S + (size_t)(r0 + rr + i) * ss + c0 + cc);
            T[rr + i][cc + 0] = v.x; T[rr + i][cc + 1] = v.y;
            T[rr + i][cc + 2] = v.z; T[rr + i][cc + 3] = v.w;
        }
    }
    __syncthreads();
    int cr = t >> 2, rc = (t & 3) * 16;
    u32 o[8];
#pragma unroll
    for (int j = 0; j < 8; ++j)
        o[j] = packh(T[rc + 2 * j][cr], T[rc + 2 * j + 1][cr]);
    u16* d = D + (size_t)(c0 + cr) * ds + r0 + rc;
    *(uint4*)(d)     = make_uint4(o[0], o[1], o[2], o[3]);
    *(uint4*)(d + 8) = make_uint4(o[4], o[5], o[6], o[7]);
}

// ---------------------------------------------------------------------------
// Kernel 3a (proven): WoT[j][k] fp16 = Wo[k][j] f32.
// ---------------------------------------------------------------------------
__global__ __launch_bounds__(256) void wo_convert(
    const float* __restrict__ Wo, u16* __restrict__ WoT)
{
    const int n0 = blockIdx.x * 64, k0 = blockIdx.y * 64;
    __shared__ float T[64][65];
    const int t = threadIdx.x;
    {
        int kr = (t >> 4) * 4;
        int nc = (t & 15) * 4;
#pragma unroll
        for (int i = 0; i < 4; ++i) {
            float4 v = *(const float4*)(Wo + (size_t)(k0 + kr + i) * DMODEL + n0 + nc);
            T[kr + i][nc + 0] = v.x; T[kr + i][nc + 1] = v.y;
            T[kr + i][nc + 2] = v.z; T[kr + i][nc + 3] = v.w;
        }
    }
    __syncthreads();
    int n = t >> 2, kc = (t & 3) * 16;
    u32 o[8];
#pragma unroll
    for (int j = 0; j < 8; ++j)
        o[j] = packh(T[kc + j * 2][n], T[kc + j * 2 + 1][n]);
    u16* dst = WoT + (size_t)(n0 + n) * DMODEL + k0 + kc;
    *(uint4*)(dst)     = make_uint4(o[0], o[1], o[2], o[3]);
    *(uint4*)(dst + 8) = make_uint4(o[4], o[5], o[6], o[7]);
}

// ---------------------------------------------------------------------------
// Kernel 1 (MFMA): batched GEMM C[z][M][N] = A[z] (M x KLEN, n-contig)
//                  x B[z]^T (N x KLEN, n-contig) + bias, f16 out.
// Body == proven out_gemm_mfma (128x128 tile, BK=64, 2x2 waves of 64x64,
// gl2lds w16 + both-sides XOR swizzle). KLEN = SEQ = 4096.
// bias_on_row: bias[M-row] (K-proj, be[k]); else bias[N-col] (V-proj, bf[k]).
// ---------------------------------------------------------------------------
__global__ __launch_bounds__(256) void proj_gemm(
    const u16* __restrict__ A, const u16* __restrict__ B,
    const float* __restrict__ bias, u16* __restrict__ Cout,
    int bias_on_row, size_t a_batch, size_t b_batch,
    int c_row_stride, size_t c_batch)
{
    const u16* Ab = A + (size_t)blockIdx.z * a_batch;
    const u16* Bb = B + (size_t)blockIdx.z * b_batch;
    u16* Cb       = Cout + (size_t)blockIdx.z * c_batch;
    const int c0 = blockIdx.x * 128;
    const int r0 = blockIdx.y * 128;
    const int t  = threadIdx.x;
    const int lane = t & 63;
    const int w  = t >> 6;
    const int wr = w >> 1, wc = w & 1;     // 2x2 wave grid, 64x64 each
    const int q  = lane >> 4, c = lane & 15;

    __shared__ u16 As[128 * 64];   // 16 KB, swizzled storage
    __shared__ u16 Bs[128 * 64];   // 16 KB

    f32x4 acc[4][4];
#pragma unroll
    for (int m = 0; m < 4; ++m)
#pragma unroll
        for (int n = 0; n < 4; ++n) acc[m][n] = (f32x4){0.f, 0.f, 0.f, 0.f};

    for (int k0 = 0; k0 < SEQ; k0 += 64) {
#pragma unroll
        for (int i = 0; i < 4; ++i) {
            int li  = i * 256 + t;
            int row = li >> 3;
            int c8  = (li & 7) ^ (row & 7);
            gl2lds16(Ab + (size_t)(r0 + row) * SEQ + k0 + c8 * 8, (u16*)As + (size_t)li * 8);
            gl2lds16(Bb + (size_t)(c0 + row) * SEQ + k0 + c8 * 8, (u16*)Bs + (size_t)li * 8);
        }
        __syncthreads();

#pragma unroll
        for (int s = 0; s < 2; ++s) {
            f16x8 af[4], bf[4];
#pragma unroll
            for (int m = 0; m < 4; ++m) {
                int row = wr * 64 + m * 16 + c;
                int c8  = (s * 4 + q) ^ (row & 7);
                af[m] = *(const f16x8*)&As[row * 64 + c8 * 8];
            }
#pragma unroll
            for (int n = 0; n < 4; ++n) {
                int row = wc * 64 + n * 16 + c;
                int c8  = (s * 4 + q) ^ (row & 7);
                bf[n] = *(const f16x8*)&Bs[row * 64 + c8 * 8];
            }
#pragma unroll
            for (int m = 0; m < 4; ++m)
#pragma unroll
                for (int n = 0; n < 4; ++n)
                    acc[m][n] = __builtin_amdgcn_mfma_f32_16x16x32_f16(af[m], bf[n], acc[m][n], 0, 0, 0);
        }
        __syncthreads();
    }

    // epilogue: C/D layout col=lane&15, row=q*4+r. f16 scalar stores.
    if (bias_on_row) {
#pragma unroll
        for (int m = 0; m < 4; ++m) {
            int rowb = r0 + wr * 64 + m * 16 + q * 4;
#pragma unroll
            for (int r = 0; r < 4; ++r) {
                float bv = bias[rowb + r];
                u16* dst = Cb + (size_t)(rowb + r) * c_row_stride + c0 + wc * 64 + c;
#pragma unroll
                for (int n = 0; n < 4; ++n) dst[n * 16] = f2h(acc[m][n][r] + bv);
            }
        }
    } else {
        float bv[4];
#pragma unroll
        for (int n = 0; n < 4; ++n) bv[n] = bias[c0 + wc * 64 + n * 16 + c];
#pragma unroll
        for (int m = 0; m < 4; ++m) {
            int rowb = r0 + wr * 64 + m * 16 + q * 4;
#pragma unroll
            for (int r = 0; r < 4; ++r) {
                u16* dst = Cb + (size_t)(rowb + r) * c_row_stride + c0 + wc * 64 + c;
#pragma unroll
                for (int n = 0; n < 4; ++n) dst[n * 16] = f2h(acc[m][n][r] + bv[n]);
            }
        }
    }
}

// ---------------------------------------------------------------------------
// Kernel 2 (MFMA, f16): fused scores+softmax+PV. Block = 64 Q-rows x (b,h),
// 4 waves, wave w owns rows w*16..w*16+15 end-to-end.
// R10 change: K-operand from KpFull[b][lk][dm] (row stride DMODEL);
//             V-operand from VpFull[b][dm][lk] (row stride LK).
// ---------------------------------------------------------------------------
__global__ __launch_bounds__(256) void attn_mfma(
    const float* __restrict__ Qin, const u16* __restrict__ KpF,
    const u16* __restrict__ VpF,   u16* __restrict__ AO)
{
    const int bh = blockIdx.y, b = bh >> 4, h = bh & 15;
    const int n0 = blockIdx.x * 64;
    const int t  = threadIdx.x;
    const int w    = t >> 6;          // wave 0..3
    const int lane = t & 63;
    const int q    = lane >> 4;       // quad 0..3
    const int c    = lane & 15;

    __shared__ u16 Qs[64][72];        // Q tile f16 (+8 pad)
    __shared__ u16 Pl[64][264];       // P tile f16 (+8 pad)

    // ---- stage Q (fp32 -> f16), wave w stages its own 16 rows ----
    {
        int lr = lane >> 2, col0 = (lane & 3) * 16;
        const float* src = Qin + ((size_t)b * SEQ + n0 + w * 16 + lr) * DMODEL + h * DK + col0;
        float4 f0 = ((const float4*)src)[0];
        float4 f1 = ((const float4*)src)[1];
        float4 f2 = ((const float4*)src)[2];
        float4 f3 = ((const float4*)src)[3];
        uint4 p0, p1;
        p0.x = packh(f0.x, f0.y); p0.y = packh(f0.z, f0.w);
        p0.z = packh(f1.x, f1.y); p0.w = packh(f1.z, f1.w);
        p1.x = packh(f2.x, f2.y); p1.y = packh(f2.z, f2.w);
        p1.z = packh(f3.x, f3.y); p1.w = packh(f3.z, f3.w);
        *(uint4*)&Qs[w * 16 + lr][col0]     = p0;
        *(uint4*)&Qs[w * 16 + lr][col0 + 8] = p1;
    }
    __syncthreads();

    // ---- A-fragments for QK^T (row m = w*16 + c, k = d) ----
    f16x8 a0 = *(const f16x8*)&Qs[w * 16 + c][q * 8];
    f16x8 a1 = *(const f16x8*)&Qs[w * 16 + c][32 + q * 8];

    // ---- scores: 16 col-tiles of 16 lk each; B-frags straight from L2 ----
    f32x4 sc[16];
#pragma unroll
    for (int nt = 0; nt < 16; ++nt) sc[nt] = (f32x4){0.f, 0.f, 0.f, 0.f};

    const u16* kb = KpF + (size_t)b * LK * DMODEL + h * DK;
#pragma unroll
    for (int nt = 0; nt < 16; ++nt) {
        const u16* kp = kb + (size_t)(nt * 16 + c) * DMODEL + q * 8;
        f16x8 b0 = *(const f16x8*)(kp);
        f16x8 b1 = *(const f16x8*)(kp + 32);
        sc[nt] = __builtin_amdgcn_mfma_f32_16x16x32_f16(a0, b0, sc[nt], 0, 0, 0);
        sc[nt] = __builtin_amdgcn_mfma_f32_16x16x32_f16(a1, b1, sc[nt], 0, 0, 0);
    }

    // ---- softmax over 256 cols, entirely in registers ----
    float mx[4] = {-1e30f, -1e30f, -1e30f, -1e30f};
#pragma unroll
    for (int nt = 0; nt < 16; ++nt) {
        sc[nt] *= 0.125f;   // 1/sqrt(DK)
#pragma unroll
        for (int r = 0; r < 4; ++r) mx[r] = fmaxf(mx[r], sc[nt][r]);
    }
#pragma unroll
    for (int d = 1; d < 16; d <<= 1)
#pragma unroll
        for (int r = 0; r < 4; ++r) mx[r] = fmaxf(mx[r], __shfl_xor(mx[r], d, 64));

    float sm[4] = {0.f, 0.f, 0.f, 0.f};
#pragma unroll
    for (int nt = 0; nt < 16; ++nt)
#pragma unroll
        for (int r = 0; r < 4; ++r) {
            float e = __expf(sc[nt][r] - mx[r]);
            sc[nt][r] = e;
            sm[r] += e;
        }
#pragma unroll
    for (int d = 1; d < 16; d <<= 1)
#pragma unroll
        for (int r = 0; r < 4; ++r) sm[r] += __shfl_xor(sm[r], d, 64);
    float inv[4];
#pragma unroll
    for (int r = 0; r < 4; ++r) inv[r] = 1.0f / sm[r];

    // ---- P: C-layout regs -> LDS (row-major f16) for A-operand re-read ----
#pragma unroll
    for (int nt = 0; nt < 16; ++nt)
#pragma unroll
        for (int r = 0; r < 4; ++r)
            Pl[w * 16 + q * 4 + r][nt * 16 + c] = f2h(sc[nt][r] * inv[r]);

    // ---- PV: out[16 x 64] per wave; A from LDS, B from VpFull (L2) ----
    f32x4 ov[4];
#pragma unroll
    for (int nt = 0; nt < 4; ++nt) ov[nt] = (f32x4){0.f, 0.f, 0.f, 0.f};
    const u16* vb = VpF + ((size_t)b * DMODEL + h * DK) * LK;
#pragma unroll
    for (int ks = 0; ks < 8; ++ks) {
        f16x8 pa = *(const f16x8*)&Pl[w * 16 + c][ks * 32 + q * 8];
#pragma unroll
        for (int nt = 0; nt < 4; ++nt) {
            f16x8 vf = *(const f16x8*)(vb + (size_t)(nt * 16 + c) * LK + ks * 32 + q * 8);
            ov[nt] = __builtin_amdgcn_mfma_f32_16x16x32_f16(pa, vf, ov[nt], 0, 0, 0);
        }
    }

    // ---- stage out tile into reused Qs (f16), then coalesced 16B stores ----
#pragma unroll
    for (int nt = 0; nt < 4; ++nt)
#pragma unroll
        for (int r = 0; r < 4; ++r)
            Qs[w * 16 + q * 4 + r][nt * 16 + c] = f2h(ov[nt][r]);

#pragma unroll
    for (int pass = 0; pass < 2; ++pass) {
        int lr  = w * 16 + pass * 8 + (lane >> 3);
        int col = (lane & 7) * 8;
        uint4 vv = *(uint4*)&Qs[lr][col];
        *(uint4*)(AO + ((size_t)b * SEQ + n0 + lr) * DMODEL + h * DK + col) = vv;
    }
}

// ---------------------------------------------------------------------------
// Kernel 3 (MFMA, proven): Out[16384][1024] = AO(f16) @ WoT^T(f16) + bo.
// 128x128 tile, BK=64, 4 waves 2x2, f16 16x16x32, gl2lds w16 + T2 swizzle.
// ---------------------------------------------------------------------------
#define OBM 128
#define OBN 128
#define OBK 64

__global__ __launch_bounds__(256) void out_gemm_mfma(
    const u16* __restrict__ AO, const u16* __restrict__ WoT,
    const float* __restrict__ bo, float* __restrict__ Out)
{
    const int c0 = blockIdx.x * OBN;
    const int r0 = blockIdx.y * OBM;
    const int t  = threadIdx.x;
    const int lane = t & 63;
    const int w  = t >> 6;
    const int wr = w >> 1, wc = w & 1;     // 2x2 wave grid, 64x64 each
    const int q  = lane >> 4, c = lane & 15;

    __shared__ u16 As[OBM * OBK];   // 16 KB, swizzled storage
    __shared__ u16 Bs[OBN * OBK];   // 16 KB

    f32x4 acc[4][4];
#pragma unroll
    for (int m = 0; m < 4; ++m)
#pragma unroll
        for (int n = 0; n < 4; ++n) acc[m][n] = (f32x4){0.f, 0.f, 0.f, 0.f};

    for (int k0 = 0; k0 < DMODEL; k0 += OBK) {
#pragma unroll
        for (int i = 0; i < 4; ++i) {
            int li  = i * 256 + t;
            int row = li >> 3;
            int c8  = (li & 7) ^ (row & 7);
            gl2lds16(AO  + (size_t)(r0 + row) * DMODEL + k0 + c8 * 8, (u16*)As + (size_t)li * 8);
            gl2lds16(WoT + (size_t)(c0 + row) * DMODEL + k0 + c8 * 8, (u16*)Bs + (size_t)li * 8);
        }
        __syncthreads();

#pragma unroll
        for (int s = 0; s < 2; ++s) {
            f16x8 af[4], bf[4];
#pragma unroll
            for (int m = 0; m < 4; ++m) {
                int row = wr * 64 + m * 16 + c;
                int c8  = (s * 4 + q) ^ (row & 7);
                af[m] = *(const f16x8*)&As[row * 64 + c8 * 8];
            }
#pragma unroll
            for (int n = 0; n < 4; ++n) {
                int row = wc * 64 + n * 16 + c;
                int c8  = (s * 4 + q) ^ (row & 7);
                bf[n] = *(const f16x8*)&Bs[row * 64 + c8 * 8];
            }
#pragma unroll
            for (int m = 0; m < 4; ++m)
#pragma unroll
                for (int n = 0; n < 4; ++n)
                    acc[m][n] = __builtin_amdgcn_mfma_f32_16x16x32_f16(af[m], bf[n], acc[m][n], 0, 0, 0);
        }
        __syncthreads();
    }

    float bv[4];
#pragma unroll
    for (int n = 0; n < 4; ++n) bv[n] = bo[c0 + wc * 64 + n * 16 + c];
#pragma unroll
    for (int m = 0; m < 4; ++m) {
        int rowb = r0 + wr * 64 + m * 16 + q * 4;
#pragma unroll
        for (int r = 0; r < 4; ++r) {
            float* dst = Out + (size_t)(rowb + r) * DMODEL + c0 + wc * 64 + c;
#pragma unroll
            for (int n = 0; n < 4; ++n) dst[n * 16] = acc[m][n][r] + bv[n];
        }
    }
}

// ---------------------------------------------------------------------------
extern "C" void kernel_launch(void* const* d_in, const int* in_sizes, int n_in,
                              void* d_out, int out_size, void* d_ws, size_t ws_size,
                              hipStream_t stream)
{
    const float* K   = (const float*)d_in[0];
    const float* Q   = (const float*)d_in[1];
    const float* V   = (const float*)d_in[2];
    const float* We  = (const float*)d_in[3];
    const float* be  = (const float*)d_in[4];
    const float* Wf  = (const float*)d_in[5];
    const float* bfp = (const float*)d_in[6];
    const float* Wo  = (const float*)d_in[7];
    const float* bo  = (const float*)d_in[8];
    float* Out = (float*)d_out;

    // ws (f16), total 39.5MB (== R6/R9 proven size), serial aliasing:
    //   [0,2MB)    KpF  [BB][LK][DMODEL]
    //   [2,4MB)    VpF  [BB][DMODEL][LK]
    //   [4,37.5)   BIG  : KT -> VT -> AO     (33.5MB)
    //   [37.5,39.5) Wsm : WeT -> WfT -> WoT  (2MB)
    u16* KpF = (u16*)d_ws;
    u16* VpF = KpF + (size_t)BB * LK * DMODEL;
    u16* BIG = VpF + (size_t)BB * DMODEL * LK;
    u16* Wsm = BIG + (size_t)BB * SEQ * DMODEL;

    // 1. WeT[k][n] ; 2. KT[b][dm][n] ; 3. KpF[b][k][dm] = WeT @ KT + be[k]
    tconv<<<dim3(SEQ / 64, LK / 64, 1), 256, 0, stream>>>(We, Wsm, LK, SEQ, 0, 0);
    tconv<<<dim3(SEQ / 64, DMODEL / 64, BB), 256, 0, stream>>>(
        K, BIG, DMODEL, SEQ, (size_t)SEQ * DMODEL, (size_t)DMODEL * SEQ);
    proj_gemm<<<dim3(DMODEL / 128, LK / 128, BB), 256, 0, stream>>>(
        Wsm, BIG, be, KpF, 1, (size_t)0, (size_t)DMODEL * SEQ, DMODEL, (size_t)LK * DMODEL);

    // 4. WfT[k][n] ; 5. VT[b][dm][n] ; 6. VpF[b][dm][k] = VT @ WfT + bf[k]
    tconv<<<dim3(SEQ / 64, LK / 64, 1), 256, 0, stream>>>(Wf, Wsm, LK, SEQ, 0, 0);
    tconv<<<dim3(SEQ / 64, DMODEL / 64, BB), 256, 0, stream>>>(
        V, BIG, DMODEL, SEQ, (size_t)SEQ * DMODEL, (size_t)DMODEL * SEQ);
    proj_gemm<<<dim3(LK / 128, DMODEL / 128, BB), 256, 0, stream>>>(
        BIG, Wsm, bfp, VpF, 0, (size_t)DMODEL * SEQ, (size_t)0, LK, (size_t)DMODEL * LK);

    // 7. WoT ; 8. attn (AO overwrites BIG) ; 9. out GEMM
    wo_convert<<<dim3(DMODEL / 64, DMODEL / 64), 256, 0, stream>>>(Wo, Wsm);
    attn_mfma<<<dim3(SEQ / 64, BH), 256, 0, stream>>>(Q, KpF, VpF, BIG);
    out_gemm_mfma<<<dim3(DMODEL / OBN, (BB * SEQ) / OBM), 256, 0, stream>>>(BIG, Wsm, bo, Out);
}

// Round 6
// 528.347 us; speedup vs baseline: 1.1870x; 1.0330x over previous
//
#include <hip/hip_runtime.h>
#include <hip/hip_bf16.h>

// Problem constants (compile-time; n_heads input d_in[9] ignored).
// Inputs/outputs FLOAT32 (per reference). Intermediates fp16 in d_ws.
// R11: (a) attn LDS union: Qs folded into Pl buffer (all phases wave-local
//      rows) -> 43KB->33KB, 3->4 blocks/CU. (b) proj_gemm double-buffered
//      (2-phase prefetch): at 64 blocks (1/CU) there is no TLP, so explicit
//      dbuf hides the 32KB/K-step staging latency. Everything else = R10.
#define BB      4
#define SEQ     4096
#define DMODEL  1024
#define NHEAD   16
#define DK      64
#define LK      256
#define BH      (BB*NHEAD)   // 64

typedef unsigned short u16;
typedef unsigned int   u32;
typedef float f32x4  __attribute__((ext_vector_type(4)));
typedef _Float16 f16x8 __attribute__((ext_vector_type(8)));

__device__ __forceinline__ u16 f2h(float f) {
    _Float16 h = (_Float16)f;                 // v_cvt_f16_f32, RNE
    u16 r; __builtin_memcpy(&r, &h, 2); return r;
}
__device__ __forceinline__ u32 packh(float a, float b) {
    return (u32)f2h(a) | ((u32)f2h(b) << 16);
}
// async global->LDS, 16B per lane (dest must be wave-uniform base + lane*16)
__device__ __forceinline__ void gl2lds16(const void* g, void* l) {
    __builtin_amdgcn_global_load_lds(
        (const __attribute__((address_space(1))) unsigned int*)g,
        (__attribute__((address_space(3))) unsigned int*)l,
        16, 0, 0);
}

// ---------------------------------------------------------------------------
// Kernel 0: generic transpose+convert, f32 [R][C] -> f16 [C][R].
// Body == proven wo_convert; strides/batch offsets as args.
// grid (R/64, C/64, batch). ss=src row stride, ds=dst row stride.
// ---------------------------------------------------------------------------
__global__ __launch_bounds__(256) void tconv(
    const float* __restrict__ src, u16* __restrict__ dst,
    int ss, int ds, size_t sbo, size_t dbo)
{
    const float* S = src + (size_t)blockIdx.z * sbo;
    u16* D         = dst + (size_t)blockIdx.z * dbo;
    const int r0 = blockIdx.x * 64;   // src rows
    const int c0 = blockIdx.y * 64;   // src cols
    __shared__ float T[64][65];
    const int t = threadIdx.x;
    {
        int rr = (t >> 4) * 4;
        int cc = (t & 15) * 4;
#pragma unroll
        for (int i = 0; i < 4; ++i) {
            float4 v = *(const float4*)(S + (size_t)(r0 + rr + i) * ss + c0 + cc);
            T[rr + i][cc + 0] = v.x; T[rr + i][cc + 1] = v.y;
            T[rr + i][cc + 2] = v.z; T[rr + i][cc + 3] = v.w;
        }
    }
    __syncthreads();
    int cr = t >> 2, rc = (t & 3) * 16;
    u32 o[8];
#pragma unroll
    for (int j = 0; j < 8; ++j)
        o[j] = packh(T[rc + 2 * j][cr], T[rc + 2 * j + 1][cr]);
    u16* d = D + (size_t)(c0 + cr) * ds + r0 + rc;
    *(uint4*)(d)     = make_uint4(o[0], o[1], o[2], o[3]);
    *(uint4*)(d + 8) = make_uint4(o[4], o[5], o[6], o[7]);
}

// ---------------------------------------------------------------------------
// Kernel 3a (proven): WoT[j][k] fp16 = Wo[k][j] f32.
// ---------------------------------------------------------------------------
__global__ __launch_bounds__(256) void wo_convert(
    const float* __restrict__ Wo, u16* __restrict__ WoT)
{
    const int n0 = blockIdx.x * 64, k0 = blockIdx.y * 64;
    __shared__ float T[64][65];
    const int t = threadIdx.x;
    {
        int kr = (t >> 4) * 4;
        int nc = (t & 15) * 4;
#pragma unroll
        for (int i = 0; i < 4; ++i) {
            float4 v = *(const float4*)(Wo + (size_t)(k0 + kr + i) * DMODEL + n0 + nc);
            T[kr + i][nc + 0] = v.x; T[kr + i][nc + 1] = v.y;
            T[kr + i][nc + 2] = v.z; T[kr + i][nc + 3] = v.w;
        }
    }
    __syncthreads();
    int n = t >> 2, kc = (t & 3) * 16;
    u32 o[8];
#pragma unroll
    for (int j = 0; j < 8; ++j)
        o[j] = packh(T[kc + j * 2][n], T[kc + j * 2 + 1][n]);
    u16* dst = WoT + (size_t)(n0 + n) * DMODEL + k0 + kc;
    *(uint4*)(dst)     = make_uint4(o[0], o[1], o[2], o[3]);
    *(uint4*)(dst + 8) = make_uint4(o[4], o[5], o[6], o[7]);
}

// ---------------------------------------------------------------------------
// Kernel 1 (MFMA, R11 double-buffered): batched GEMM
//   C[z][M][N] = A[z] (M x 4096, n-contig) x B[z]^T (N x 4096, n-contig) + bias
// 128x128 tile, BK=64, 2x2 waves, gl2lds w16 + XOR swizzle, 2-phase dbuf.
// ---------------------------------------------------------------------------
__global__ __launch_bounds__(256) void proj_gemm(
    const u16* __restrict__ A, const u16* __restrict__ B,
    const float* __restrict__ bias, u16* __restrict__ Cout,
    int bias_on_row, size_t a_batch, size_t b_batch,
    int c_row_stride, size_t c_batch)
{
    const u16* Ab = A + (size_t)blockIdx.z * a_batch;
    const u16* Bb = B + (size_t)blockIdx.z * b_batch;
    u16* Cb       = Cout + (size_t)blockIdx.z * c_batch;
    const int c0 = blockIdx.x * 128;
    const int r0 = blockIdx.y * 128;
    const int t  = threadIdx.x;
    const int lane = t & 63;
    const int w  = t >> 6;
    const int wr = w >> 1, wc = w & 1;     // 2x2 wave grid, 64x64 each
    const int q  = lane >> 4, c = lane & 15;

    __shared__ u16 As[2][128 * 64];   // 2 x 16 KB, swizzled storage
    __shared__ u16 Bs[2][128 * 64];

    auto stage = [&](int buf, int kk) {
#pragma unroll
        for (int i = 0; i < 4; ++i) {
            int li  = i * 256 + t;
            int row = li >> 3;
            int c8  = (li & 7) ^ (row & 7);
            gl2lds16(Ab + (size_t)(r0 + row) * SEQ + kk + c8 * 8, &As[buf][(size_t)li * 8]);
            gl2lds16(Bb + (size_t)(c0 + row) * SEQ + kk + c8 * 8, &Bs[buf][(size_t)li * 8]);
        }
    };

    f32x4 acc[4][4];
#pragma unroll
    for (int m = 0; m < 4; ++m)
#pragma unroll
        for (int n = 0; n < 4; ++n) acc[m][n] = (f32x4){0.f, 0.f, 0.f, 0.f};

    stage(0, 0);
    __syncthreads();                       // drains vmcnt(0) (compiler-emitted)
    int cur = 0;
    for (int k0 = 0; k0 < SEQ; k0 += 64) {
        if (k0 + 64 < SEQ) stage(cur ^ 1, k0 + 64);   // prefetch next tile

#pragma unroll
        for (int s = 0; s < 2; ++s) {
            f16x8 af[4], bf[4];
#pragma unroll
            for (int m = 0; m < 4; ++m) {
                int row = wr * 64 + m * 16 + c;
                int c8  = (s * 4 + q) ^ (row & 7);
                af[m] = *(const f16x8*)&As[cur][row * 64 + c8 * 8];
            }
#pragma unroll
            for (int n = 0; n < 4; ++n) {
                int row = wc * 64 + n * 16 + c;
                int c8  = (s * 4 + q) ^ (row & 7);
                bf[n] = *(const f16x8*)&Bs[cur][row * 64 + c8 * 8];
            }
#pragma unroll
            for (int m = 0; m < 4; ++m)
#pragma unroll
                for (int n = 0; n < 4; ++n)
                    acc[m][n] = __builtin_amdgcn_mfma_f32_16x16x32_f16(af[m], bf[n], acc[m][n], 0, 0, 0);
        }
        __syncthreads();                   // waits prefetch done + protects bufs
        cur ^= 1;
    }

    // epilogue: C/D layout col=lane&15, row=q*4+r. f16 scalar stores.
    if (bias_on_row) {
#pragma unroll
        for (int m = 0; m < 4; ++m) {
            int rowb = r0 + wr * 64 + m * 16 + q * 4;
#pragma unroll
            for (int r = 0; r < 4; ++r) {
                float bv = bias[rowb + r];
                u16* dst = Cb + (size_t)(rowb + r) * c_row_stride + c0 + wc * 64 + c;
#pragma unroll
                for (int n = 0; n < 4; ++n) dst[n * 16] = f2h(acc[m][n][r] + bv);
            }
        }
    } else {
        float bv[4];
#pragma unroll
        for (int n = 0; n < 4; ++n) bv[n] = bias[c0 + wc * 64 + n * 16 + c];
#pragma unroll
        for (int m = 0; m < 4; ++m) {
            int rowb = r0 + wr * 64 + m * 16 + q * 4;
#pragma unroll
            for (int r = 0; r < 4; ++r) {
                u16* dst = Cb + (size_t)(rowb + r) * c_row_stride + c0 + wc * 64 + c;
#pragma unroll
                for (int n = 0; n < 4; ++n) dst[n * 16] = f2h(acc[m][n][r] + bv[n]);
            }
        }
    }
}

// ---------------------------------------------------------------------------
// Kernel 2 (MFMA, f16, R11 LDS-union): fused scores+softmax+PV.
// Block = 64 Q-rows x (b,h), 4 waves, wave w owns rows [w*16, w*16+16)
// of the single SM buffer at EVERY phase (Q-stage -> P -> out-stage are
// all wave-local) -> no barriers, 33KB LDS, 4 blocks/CU.
// ---------------------------------------------------------------------------
__global__ __launch_bounds__(256) void attn_mfma(
    const float* __restrict__ Qin, const u16* __restrict__ KpF,
    const u16* __restrict__ VpF,   u16* __restrict__ AO)
{
    const int bh = blockIdx.y, b = bh >> 4, h = bh & 15;
    const int n0 = blockIdx.x * 64;
    const int t  = threadIdx.x;
    const int w    = t >> 6;          // wave 0..3
    const int lane = t & 63;
    const int q    = lane >> 4;       // quad 0..3
    const int c    = lane & 15;

    __shared__ u16 SM[64][264];       // union: Q tile (cols 0..64) -> P tile -> out

    // ---- stage Q (fp32 -> f16), wave w stages its own 16 rows ----
    {
        int lr = lane >> 2, col0 = (lane & 3) * 16;
        const float* src = Qin + ((size_t)b * SEQ + n0 + w * 16 + lr) * DMODEL + h * DK + col0;
        float4 f0 = ((const float4*)src)[0];
        float4 f1 = ((const float4*)src)[1];
        float4 f2 = ((const float4*)src)[2];
        float4 f3 = ((const float4*)src)[3];
        uint4 p0, p1;
        p0.x = packh(f0.x, f0.y); p0.y = packh(f0.z, f0.w);
        p0.z = packh(f1.x, f1.y); p0.w = packh(f1.z, f1.w);
        p1.x = packh(f2.x, f2.y); p1.y = packh(f2.z, f2.w);
        p1.z = packh(f3.x, f3.y); p1.w = packh(f3.z, f3.w);
        *(uint4*)&SM[w * 16 + lr][col0]     = p0;
        *(uint4*)&SM[w * 16 + lr][col0 + 8] = p1;
    }
    // no barrier: all SM accesses in this kernel are wave-local rows.

    // ---- A-fragments for QK^T (row m = w*16 + c, k = d) ----
    f16x8 a0 = *(const f16x8*)&SM[w * 16 + c][q * 8];
    f16x8 a1 = *(const f16x8*)&SM[w * 16 + c][32 + q * 8];

    // ---- scores: 16 col-tiles of 16 lk each; B-frags straight from L2 ----
    f32x4 sc[16];
#pragma unroll
    for (int nt = 0; nt < 16; ++nt) sc[nt] = (f32x4){0.f, 0.f, 0.f, 0.f};

    const u16* kb = KpF + (size_t)b * LK * DMODEL + h * DK;
#pragma unroll
    for (int nt = 0; nt < 16; ++nt) {
        const u16* kp = kb + (size_t)(nt * 16 + c) * DMODEL + q * 8;
        f16x8 b0 = *(const f16x8*)(kp);
        f16x8 b1 = *(const f16x8*)(kp + 32);
        sc[nt] = __builtin_amdgcn_mfma_f32_16x16x32_f16(a0, b0, sc[nt], 0, 0, 0);
        sc[nt] = __builtin_amdgcn_mfma_f32_16x16x32_f16(a1, b1, sc[nt], 0, 0, 0);
    }

    // ---- softmax over 256 cols, entirely in registers ----
    float mx[4] = {-1e30f, -1e30f, -1e30f, -1e30f};
#pragma unroll
    for (int nt = 0; nt < 16; ++nt) {
        sc[nt] *= 0.125f;   // 1/sqrt(DK)
#pragma unroll
        for (int r = 0; r < 4; ++r) mx[r] = fmaxf(mx[r], sc[nt][r]);
    }
#pragma unroll
    for (int d = 1; d < 16; d <<= 1)
#pragma unroll
        for (int r = 0; r < 4; ++r) mx[r] = fmaxf(mx[r], __shfl_xor(mx[r], d, 64));

    float sm[4] = {0.f, 0.f, 0.f, 0.f};
#pragma unroll
    for (int nt = 0; nt < 16; ++nt)
#pragma unroll
        for (int r = 0; r < 4; ++r) {
            float e = __expf(sc[nt][r] - mx[r]);
            sc[nt][r] = e;
            sm[r] += e;
        }
#pragma unroll
    for (int d = 1; d < 16; d <<= 1)
#pragma unroll
        for (int r = 0; r < 4; ++r) sm[r] += __shfl_xor(sm[r], d, 64);
    float inv[4];
#pragma unroll
    for (int r = 0; r < 4; ++r) inv[r] = 1.0f / sm[r];

    // ---- P: C-layout regs -> SM rows (overwrites Q, now dead) ----
#pragma unroll
    for (int nt = 0; nt < 16; ++nt)
#pragma unroll
        for (int r = 0; r < 4; ++r)
            SM[w * 16 + q * 4 + r][nt * 16 + c] = f2h(sc[nt][r] * inv[r]);

    // ---- PV: out[16 x 64] per wave; A from SM, B from VpFull (L2) ----
    f32x4 ov[4];
#pragma unroll
    for (int nt = 0; nt < 4; ++nt) ov[nt] = (f32x4){0.f, 0.f, 0.f, 0.f};
    const u16* vb = VpF + ((size_t)b * DMODEL + h * DK) * LK;
#pragma unroll
    for (int ks = 0; ks < 8; ++ks) {
        f16x8 pa = *(const f16x8*)&SM[w * 16 + c][ks * 32 + q * 8];
#pragma unroll
        for (int nt = 0; nt < 4; ++nt) {
            f16x8 vf = *(const f16x8*)(vb + (size_t)(nt * 16 + c) * LK + ks * 32 + q * 8);
            ov[nt] = __builtin_amdgcn_mfma_f32_16x16x32_f16(pa, vf, ov[nt], 0, 0, 0);
        }
    }

    // ---- stage out tile into SM (overwrites P, now dead), coalesced stores ----
#pragma unroll
    for (int nt = 0; nt < 4; ++nt)
#pragma unroll
        for (int r = 0; r < 4; ++r)
            SM[w * 16 + q * 4 + r][nt * 16 + c] = f2h(ov[nt][r]);

#pragma unroll
    for (int pass = 0; pass < 2; ++pass) {
        int lr  = w * 16 + pass * 8 + (lane >> 3);
        int col = (lane & 7) * 8;
        uint4 vv = *(uint4*)&SM[lr][col];
        *(uint4*)(AO + ((size_t)b * SEQ + n0 + lr) * DMODEL + h * DK + col) = vv;
    }
}

// ---------------------------------------------------------------------------
// Kernel 3 (MFMA, proven): Out[16384][1024] = AO(f16) @ WoT^T(f16) + bo.
// 128x128 tile, BK=64, 4 waves 2x2, f16 16x16x32, gl2lds w16 + T2 swizzle.
// (4 blocks/CU -> TLP hides staging; no dbuf needed here.)
// ---------------------------------------------------------------------------
#define OBM 128
#define OBN 128
#define OBK 64

__global__ __launch_bounds__(256) void out_gemm_mfma(
    const u16* __restrict__ AO, const u16* __restrict__ WoT,
    const float* __restrict__ bo, float* __restrict__ Out)
{
    const int c0 = blockIdx.x * OBN;
    const int r0 = blockIdx.y * OBM;
    const int t  = threadIdx.x;
    const int lane = t & 63;
    const int w  = t >> 6;
    const int wr = w >> 1, wc = w & 1;     // 2x2 wave grid, 64x64 each
    const int q  = lane >> 4, c = lane & 15;

    __shared__ u16 As[OBM * OBK];   // 16 KB, swizzled storage
    __shared__ u16 Bs[OBN * OBK];   // 16 KB

    f32x4 acc[4][4];
#pragma unroll
    for (int m = 0; m < 4; ++m)
#pragma unroll
        for (int n = 0; n < 4; ++n) acc[m][n] = (f32x4){0.f, 0.f, 0.f, 0.f};

    for (int k0 = 0; k0 < DMODEL; k0 += OBK) {
#pragma unroll
        for (int i = 0; i < 4; ++i) {
            int li  = i * 256 + t;
            int row = li >> 3;
            int c8  = (li & 7) ^ (row & 7);
            gl2lds16(AO  + (size_t)(r0 + row) * DMODEL + k0 + c8 * 8, (u16*)As + (size_t)li * 8);
            gl2lds16(WoT + (size_t)(c0 + row) * DMODEL + k0 + c8 * 8, (u16*)Bs + (size_t)li * 8);
        }
        __syncthreads();

#pragma unroll
        for (int s = 0; s < 2; ++s) {
            f16x8 af[4], bf[4];
#pragma unroll
            for (int m = 0; m < 4; ++m) {
                int row = wr * 64 + m * 16 + c;
                int c8  = (s * 4 + q) ^ (row & 7);
                af[m] = *(const f16x8*)&As[row * 64 + c8 * 8];
            }
#pragma unroll
            for (int n = 0; n < 4; ++n) {
                int row = wc * 64 + n * 16 + c;
                int c8  = (s * 4 + q) ^ (row & 7);
                bf[n] = *(const f16x8*)&Bs[row * 64 + c8 * 8];
            }
#pragma unroll
            for (int m = 0; m < 4; ++m)
#pragma unroll
                for (int n = 0; n < 4; ++n)
                    acc[m][n] = __builtin_amdgcn_mfma_f32_16x16x32_f16(af[m], bf[n], acc[m][n], 0, 0, 0);
        }
        __syncthreads();
    }

    float bv[4];
#pragma unroll
    for (int n = 0; n < 4; ++n) bv[n] = bo[c0 + wc * 64 + n * 16 + c];
#pragma unroll
    for (int m = 0; m < 4; ++m) {
        int rowb = r0 + wr * 64 + m * 16 + q * 4;
#pragma unroll
        for (int r = 0; r < 4; ++r) {
            float* dst = Out + (size_t)(rowb + r) * DMODEL + c0 + wc * 64 + c;
#pragma unroll
            for (int n = 0; n < 4; ++n) dst[n * 16] = acc[m][n][r] + bv[n];
        }
    }
}

// ---------------------------------------------------------------------------
extern "C" void kernel_launch(void* const* d_in, const int* in_sizes, int n_in,
                              void* d_out, int out_size, void* d_ws, size_t ws_size,
                              hipStream_t stream)
{
    const float* K   = (const float*)d_in[0];
    const float* Q   = (const float*)d_in[1];
    const float* V   = (const float*)d_in[2];
    const float* We  = (const float*)d_in[3];
    const float* be  = (const float*)d_in[4];
    const float* Wf  = (const float*)d_in[5];
    const float* bfp = (const float*)d_in[6];
    const float* Wo  = (const float*)d_in[7];
    const float* bo  = (const float*)d_in[8];
    float* Out = (float*)d_out;

    // ws (f16), total 39.5MB (== R6/R9/R10 proven size), serial aliasing:
    //   [0,2MB)    KpF  [BB][LK][DMODEL]
    //   [2,4MB)    VpF  [BB][DMODEL][LK]
    //   [4,37.5)   BIG  : KT -> VT -> AO     (33.5MB)
    //   [37.5,39.5) Wsm : WeT -> WfT -> WoT  (2MB)
    u16* KpF = (u16*)d_ws;
    u16* VpF = KpF + (size_t)BB * LK * DMODEL;
    u16* BIG = VpF + (size_t)BB * DMODEL * LK;
    u16* Wsm = BIG + (size_t)BB * SEQ * DMODEL;

    // 1. WeT[k][n] ; 2. KT[b][dm][n] ; 3. KpF[b][k][dm] = WeT @ KT + be[k]
    tconv<<<dim3(SEQ / 64, LK / 64, 1), 256, 0, stream>>>(We, Wsm, LK, SEQ, 0, 0);
    tconv<<<dim3(SEQ / 64, DMODEL / 64, BB), 256, 0, stream>>>(
        K, BIG, DMODEL, SEQ, (size_t)SEQ * DMODEL, (size_t)DMODEL * SEQ);
    proj_gemm<<<dim3(DMODEL / 128, LK / 128, BB), 256, 0, stream>>>(
        Wsm, BIG, be, KpF, 1, (size_t)0, (size_t)DMODEL * SEQ, DMODEL, (size_t)LK * DMODEL);

    // 4. WfT[k][n] ; 5. VT[b][dm][n] ; 6. VpF[b][dm][k] = VT @ WfT + bf[k]
    tconv<<<dim3(SEQ / 64, LK / 64, 1), 256, 0, stream>>>(Wf, Wsm, LK, SEQ, 0, 0);
    tconv<<<dim3(SEQ / 64, DMODEL / 64, BB), 256, 0, stream>>>(
        V, BIG, DMODEL, SEQ, (size_t)SEQ * DMODEL, (size_t)DMODEL * SEQ);
    proj_gemm<<<dim3(LK / 128, DMODEL / 128, BB), 256, 0, stream>>>(
        BIG, Wsm, bfp, VpF, 0, (size_t)DMODEL * SEQ, (size_t)0, LK, (size_t)DMODEL * LK);

    // 7. WoT ; 8. attn (AO overwrites BIG) ; 9. out GEMM
    wo_convert<<<dim3(DMODEL / 64, DMODEL / 64), 256, 0, stream>>>(Wo, Wsm);
    attn_mfma<<<dim3(SEQ / 64, BH), 256, 0, stream>>>(Q, KpF, VpF, BIG);
    out_gemm_mfma<<<dim3(DMODEL / OBN, (BB * SEQ) / OBM), 256, 0, stream>>>(BIG, Wsm, bo, Out);
}

// Round 7
// 395.475 us; speedup vs baseline: 1.5858x; 1.3360x over previous
//
#include <hip/hip_runtime.h>
#include <hip/hip_bf16.h>

// R12: (a) attn stages K-tile and V-tile into LDS via gl2lds + proven XOR
//      swizzle; K-buffer unions with P (1 barrier). Kills the per-wave
//      scattered-L2-load latency chain (R11: MfmaUtil 4.5, all pipes idle).
//      (b) proj_both: K-proj + V-proj merged into one 128-block launch
//      (per-block == one of the two proven R11 configs). Needs KT+VT
//      concurrently -> gated on ws_size >= 72MB; else exact R11 serial path.
#define BB      4
#define SEQ     4096
#define DMODEL  1024
#define NHEAD   16
#define DK      64
#define LK      256
#define BH      (BB*NHEAD)   // 64

typedef unsigned short u16;
typedef unsigned int   u32;
typedef float f32x4  __attribute__((ext_vector_type(4)));
typedef _Float16 f16x8 __attribute__((ext_vector_type(8)));

__device__ __forceinline__ u16 f2h(float f) {
    _Float16 h = (_Float16)f;                 // v_cvt_f16_f32, RNE
    u16 r; __builtin_memcpy(&r, &h, 2); return r;
}
__device__ __forceinline__ u32 packh(float a, float b) {
    return (u32)f2h(a) | ((u32)f2h(b) << 16);
}
// async global->LDS, 16B per lane (dest must be wave-uniform base + lane*16)
__device__ __forceinline__ void gl2lds16(const void* g, void* l) {
    __builtin_amdgcn_global_load_lds(
        (const __attribute__((address_space(1))) unsigned int*)g,
        (__attribute__((address_space(3))) unsigned int*)l,
        16, 0, 0);
}

// ---------------------------------------------------------------------------
// Kernel 0: generic transpose+convert, f32 [R][C] -> f16 [C][R].
// ---------------------------------------------------------------------------
__global__ __launch_bounds__(256) void tconv(
    const float* __restrict__ src, u16* __restrict__ dst,
    int ss, int ds, size_t sbo, size_t dbo)
{
    const float* S = src + (size_t)blockIdx.z * sbo;
    u16* D         = dst + (size_t)blockIdx.z * dbo;
    const int r0 = blockIdx.x * 64;   // src rows
    const int c0 = blockIdx.y * 64;   // src cols
    __shared__ float T[64][65];
    const int t = threadIdx.x;
    {
        int rr = (t >> 4) * 4;
        int cc = (t & 15) * 4;
#pragma unroll
        for (int i = 0; i < 4; ++i) {
            float4 v = *(const float4*)(S + (size_t)(r0 + rr + i) * ss + c0 + cc);
            T[rr + i][cc + 0] = v.x; T[rr + i][cc + 1] = v.y;
            T[rr + i][cc + 2] = v.z; T[rr + i][cc + 3] = v.w;
        }
    }
    __syncthreads();
    int cr = t >> 2, rc = (t & 3) * 16;
    u32 o[8];
#pragma unroll
    for (int j = 0; j < 8; ++j)
        o[j] = packh(T[rc + 2 * j][cr], T[rc + 2 * j + 1][cr]);
    u16* d = D + (size_t)(c0 + cr) * ds + r0 + rc;
    *(uint4*)(d)     = make_uint4(o[0], o[1], o[2], o[3]);
    *(uint4*)(d + 8) = make_uint4(o[4], o[5], o[6], o[7]);
}

// ---------------------------------------------------------------------------
// Kernel 3a (proven): WoT[j][k] fp16 = Wo[k][j] f32.
// ---------------------------------------------------------------------------
__global__ __launch_bounds__(256) void wo_convert(
    const float* __restrict__ Wo, u16* __restrict__ WoT)
{
    const int n0 = blockIdx.x * 64, k0 = blockIdx.y * 64;
    __shared__ float T[64][65];
    const int t = threadIdx.x;
    {
        int kr = (t >> 4) * 4;
        int nc = (t & 15) * 4;
#pragma unroll
        for (int i = 0; i < 4; ++i) {
            float4 v = *(const float4*)(Wo + (size_t)(k0 + kr + i) * DMODEL + n0 + nc);
            T[kr + i][nc + 0] = v.x; T[kr + i][nc + 1] = v.y;
            T[kr + i][nc + 2] = v.z; T[kr + i][nc + 3] = v.w;
        }
    }
    __syncthreads();
    int n = t >> 2, kc = (t & 3) * 16;
    u32 o[8];
#pragma unroll
    for (int j = 0; j < 8; ++j)
        o[j] = packh(T[kc + j * 2][n], T[kc + j * 2 + 1][n]);
    u16* dst = WoT + (size_t)(n0 + n) * DMODEL + k0 + kc;
    *(uint4*)(dst)     = make_uint4(o[0], o[1], o[2], o[3]);
    *(uint4*)(dst + 8) = make_uint4(o[4], o[5], o[6], o[7]);
}

// ---------------------------------------------------------------------------
// proj_gemm (R11-proven, serial fallback): batched TN GEMM, dbuf.
// ---------------------------------------------------------------------------
#define PROJ_BODY(Ab, Bb, bias, Cb, bias_on_row, c_row_stride, c0, r0)          \
    const int t  = threadIdx.x;                                                 \
    const int lane = t & 63;                                                    \
    const int w  = t >> 6;                                                      \
    const int wr = w >> 1, wc = w & 1;                                          \
    const int q  = lane >> 4, c = lane & 15;                                    \
    __shared__ u16 As[2][128 * 64];                                             \
    __shared__ u16 Bs[2][128 * 64];                                             \
    auto stage = [&](int buf, int kk) {                                         \
        _Pragma("unroll")                                                       \
        for (int i = 0; i < 4; ++i) {                                           \
            int li  = i * 256 + t;                                              \
            int row = li >> 3;                                                  \
            int c8  = (li & 7) ^ (row & 7);                                     \
            gl2lds16(Ab + (size_t)(r0 + row) * SEQ + kk + c8 * 8, &As[buf][(size_t)li * 8]); \
            gl2lds16(Bb + (size_t)(c0 + row) * SEQ + kk + c8 * 8, &Bs[buf][(size_t)li * 8]); \
        }                                                                       \
    };                                                                          \
    f32x4 acc[4][4];                                                            \
    _Pragma("unroll")                                                           \
    for (int m = 0; m < 4; ++m)                                                 \
        _Pragma("unroll")                                                       \
        for (int n = 0; n < 4; ++n) acc[m][n] = (f32x4){0.f, 0.f, 0.f, 0.f};    \
    stage(0, 0);                                                                \
    __syncthreads();                                                            \
    int cur = 0;                                                                \
    for (int k0 = 0; k0 < SEQ; k0 += 64) {                                      \
        if (k0 + 64 < SEQ) stage(cur ^ 1, k0 + 64);                             \
        _Pragma("unroll")                                                       \
        for (int s = 0; s < 2; ++s) {                                           \
            f16x8 af[4], bf[4];                                                 \
            _Pragma("unroll")                                                   \
            for (int m = 0; m < 4; ++m) {                                       \
                int row = wr * 64 + m * 16 + c;                                 \
                int c8  = (s * 4 + q) ^ (row & 7);                              \
                af[m] = *(const f16x8*)&As[cur][row * 64 + c8 * 8];             \
            }                                                                   \
            _Pragma("unroll")                                                   \
            for (int n = 0; n < 4; ++n) {                                       \
                int row = wc * 64 + n * 16 + c;                                 \
                int c8  = (s * 4 + q) ^ (row & 7);                              \
                bf[n] = *(const f16x8*)&Bs[cur][row * 64 + c8 * 8];             \
            }                                                                   \
            _Pragma("unroll")                                                   \
            for (int m = 0; m < 4; ++m)                                         \
                _Pragma("unroll")                                               \
                for (int n = 0; n < 4; ++n)                                     \
                    acc[m][n] = __builtin_amdgcn_mfma_f32_16x16x32_f16(af[m], bf[n], acc[m][n], 0, 0, 0); \
        }                                                                       \
        __syncthreads();                                                        \
        cur ^= 1;                                                               \
    }                                                                           \
    if (bias_on_row) {                                                          \
        _Pragma("unroll")                                                       \
        for (int m = 0; m < 4; ++m) {                                           \
            int rowb = r0 + wr * 64 + m * 16 + q * 4;                           \
            _Pragma("unroll")                                                   \
            for (int r = 0; r < 4; ++r) {                                       \
                float bv = bias[rowb + r];                                      \
                u16* dst = Cb + (size_t)(rowb + r) * c_row_stride + c0 + wc * 64 + c; \
                _Pragma("unroll")                                               \
                for (int n = 0; n < 4; ++n) dst[n * 16] = f2h(acc[m][n][r] + bv); \
            }                                                                   \
        }                                                                       \
    } else {                                                                    \
        float bv[4];                                                            \
        _Pragma("unroll")                                                       \
        for (int n = 0; n < 4; ++n) bv[n] = bias[c0 + wc * 64 + n * 16 + c];    \
        _Pragma("unroll")                                                       \
        for (int m = 0; m < 4; ++m) {                                           \
            int rowb = r0 + wr * 64 + m * 16 + q * 4;                           \
            _Pragma("unroll")                                                   \
            for (int r = 0; r < 4; ++r) {                                       \
                u16* dst = Cb + (size_t)(rowb + r) * c_row_stride + c0 + wc * 64 + c; \
                _Pragma("unroll")                                               \
                for (int n = 0; n < 4; ++n) dst[n * 16] = f2h(acc[m][n][r] + bv[n]); \
            }                                                                   \
        }                                                                       \
    }

__global__ __launch_bounds__(256) void proj_gemm(
    const u16* __restrict__ A, const u16* __restrict__ B,
    const float* __restrict__ bias, u16* __restrict__ Cout,
    int bias_on_row, size_t a_batch, size_t b_batch,
    int c_row_stride, size_t c_batch)
{
    const u16* Ab = A + (size_t)blockIdx.z * a_batch;
    const u16* Bb = B + (size_t)blockIdx.z * b_batch;
    u16* Cb       = Cout + (size_t)blockIdx.z * c_batch;
    const int c0 = blockIdx.x * 128;
    const int r0 = blockIdx.y * 128;
    PROJ_BODY(Ab, Bb, bias, Cb, bias_on_row, c_row_stride, c0, r0)
}

// ---------------------------------------------------------------------------
// proj_both (R12): both projections in ONE 128-block launch. Per-block
// behavior == one of the two proven R11 proj_gemm configs (flat decode).
// ---------------------------------------------------------------------------
__global__ __launch_bounds__(256) void proj_both(
    const u16* __restrict__ WeT, const u16* __restrict__ WfT,
    const u16* __restrict__ KT,  const u16* __restrict__ VT,
    const float* __restrict__ be, const float* __restrict__ bfp,
    u16* __restrict__ KpF, u16* __restrict__ VpF)
{
    const int id = blockIdx.x;
    const u16 *Ab, *Bb; const float* bias; u16* Cb;
    int bias_on_row, c_row_stride, c0, r0;
    if (id < 64) {              // K-proj: C[lk][dm] = WeT @ KT[b]^T + be[lk]
        int b = id >> 4, s = id & 15;
        c0 = (s & 7) * 128; r0 = (s >> 3) * 128;
        Ab = WeT; Bb = KT + (size_t)b * DMODEL * SEQ;
        bias = be; bias_on_row = 1;
        Cb = KpF + (size_t)b * LK * DMODEL; c_row_stride = DMODEL;
    } else {                    // V-proj: C[dm][lk] = VT[b] @ WfT^T + bf[lk]
        int j = id - 64, b = j >> 4, s = j & 15;
        c0 = (s & 1) * 128; r0 = (s >> 1) * 128;
        Ab = VT + (size_t)b * DMODEL * SEQ; Bb = WfT;
        bias = bfp; bias_on_row = 0;
        Cb = VpF + (size_t)b * DMODEL * LK; c_row_stride = LK;
    }
    PROJ_BODY(Ab, Bb, bias, Cb, bias_on_row, c_row_stride, c0, r0)
}

// ---------------------------------------------------------------------------
// Kernel 2 (R12): fused attn with K/V LDS staging.
// Per block (64 Q-rows x (b,h)): gl2lds K-tile [256][64] (XOR-swz chunks)
// and V-tile [64][256] (low-3-bit XOR-swz chunks); barrier; QK^T from LDS;
// softmax in regs; barrier; P overwrites K buffer; PV from LDS; out via QO.
// ---------------------------------------------------------------------------
__global__ __launch_bounds__(256) void attn_mfma(
    const float* __restrict__ Qin, const u16* __restrict__ KpF,
    const u16* __restrict__ VpF,   u16* __restrict__ AO)
{
    const int bh = blockIdx.y, b = bh >> 4, h = bh & 15;
    const int n0 = blockIdx.x * 64;
    const int t  = threadIdx.x;
    const int w    = t >> 6;          // wave 0..3
    const int lane = t & 63;
    const int q    = lane >> 4;       // quad 0..3
    const int c    = lane & 15;

    __shared__ u16 QO[64][72];        // Q stage -> out stage (wave-local rows)
    __shared__ u16 KP[16896];         // union: K [256][64] | P [64][264]
    __shared__ u16 Vl[16384];         // V [64][256]

    // ---- issue K-tile stage: linear dest, source chunk ^ (row&7) ----
    const u16* kbase = KpF + (size_t)b * LK * DMODEL + h * DK;
#pragma unroll
    for (int i = 0; i < 8; ++i) {
        int li = i * 256 + t;
        int row = li >> 3, ch = li & 7;             // row=lk, 8 chunks of 8 f16
        int chs = ch ^ (row & 7);
        gl2lds16(kbase + (size_t)row * DMODEL + chs * 8, KP + (size_t)li * 8);
    }
    // ---- issue V-tile stage: source low-3 chunk bits ^ (row&7) ----
    const u16* vbase = VpF + ((size_t)b * DMODEL + h * DK) * LK;
#pragma unroll
    for (int i = 0; i < 8; ++i) {
        int li = i * 256 + t;
        int row = li >> 5, ch = li & 31;            // row=d, 32 chunks of 8 f16
        int chs = (ch & 24) | ((ch & 7) ^ (row & 7));
        gl2lds16(vbase + (size_t)row * LK + chs * 8, Vl + (size_t)li * 8);
    }
    // ---- stage Q (fp32 -> f16) into QO, wave w stages its own 16 rows ----
    {
        int lr = lane >> 2, col0 = (lane & 3) * 16;
        const float* src = Qin + ((size_t)b * SEQ + n0 + w * 16 + lr) * DMODEL + h * DK + col0;
        float4 f0 = ((const float4*)src)[0];
        float4 f1 = ((const float4*)src)[1];
        float4 f2 = ((const float4*)src)[2];
        float4 f3 = ((const float4*)src)[3];
        uint4 p0, p1;
        p0.x = packh(f0.x, f0.y); p0.y = packh(f0.z, f0.w);
        p0.z = packh(f1.x, f1.y); p0.w = packh(f1.z, f1.w);
        p1.x = packh(f2.x, f2.y); p1.y = packh(f2.z, f2.w);
        p1.z = packh(f3.x, f3.y); p1.w = packh(f3.z, f3.w);
        *(uint4*)&QO[w * 16 + lr][col0]     = p0;
        *(uint4*)&QO[w * 16 + lr][col0 + 8] = p1;
    }
    __syncthreads();   // drains gl2lds (vmcnt) + Q writes (lgkm)

    // ---- A-fragments for QK^T ----
    f16x8 a0 = *(const f16x8*)&QO[w * 16 + c][q * 8];
    f16x8 a1 = *(const f16x8*)&QO[w * 16 + c][32 + q * 8];

    // ---- scores from K-LDS: B[row=nt*16+c][chunk q | 4+q], swz ^ (c&7) ----
    f32x4 sc[16];
#pragma unroll
    for (int nt = 0; nt < 16; ++nt) sc[nt] = (f32x4){0.f, 0.f, 0.f, 0.f};
#pragma unroll
    for (int nt = 0; nt < 16; ++nt) {
        int ra = (nt * 16 + c) * 64;
        f16x8 b0 = *(const f16x8*)&KP[ra + ((q ^ (c & 7)) * 8)];
        f16x8 b1 = *(const f16x8*)&KP[ra + (((4 + q) ^ (c & 7)) * 8)];
        sc[nt] = __builtin_amdgcn_mfma_f32_16x16x32_f16(a0, b0, sc[nt], 0, 0, 0);
        sc[nt] = __builtin_amdgcn_mfma_f32_16x16x32_f16(a1, b1, sc[nt], 0, 0, 0);
    }

    // ---- softmax over 256 cols, in registers ----
    float mx[4] = {-1e30f, -1e30f, -1e30f, -1e30f};
#pragma unroll
    for (int nt = 0; nt < 16; ++nt) {
        sc[nt] *= 0.125f;   // 1/sqrt(DK)
#pragma unroll
        for (int r = 0; r < 4; ++r) mx[r] = fmaxf(mx[r], sc[nt][r]);
    }
#pragma unroll
    for (int d = 1; d < 16; d <<= 1)
#pragma unroll
        for (int r = 0; r < 4; ++r) mx[r] = fmaxf(mx[r], __shfl_xor(mx[r], d, 64));

    float sm[4] = {0.f, 0.f, 0.f, 0.f};
#pragma unroll
    for (int nt = 0; nt < 16; ++nt)
#pragma unroll
        for (int r = 0; r < 4; ++r) {
            float e = __expf(sc[nt][r] - mx[r]);
            sc[nt][r] = e;
            sm[r] += e;
        }
#pragma unroll
    for (int d = 1; d < 16; d <<= 1)
#pragma unroll
        for (int r = 0; r < 4; ++r) sm[r] += __shfl_xor(sm[r], d, 64);
    float inv[4];
#pragma unroll
    for (int r = 0; r < 4; ++r) inv[r] = 1.0f / sm[r];

    __syncthreads();   // all waves done reading K region before P overwrites

    // ---- P -> KP as [64][264] (wave-local rows) ----
#pragma unroll
    for (int nt = 0; nt < 16; ++nt)
#pragma unroll
        for (int r = 0; r < 4; ++r)
            KP[(w * 16 + q * 4 + r) * 264 + nt * 16 + c] = f2h(sc[nt][r] * inv[r]);

    // ---- PV: pa from P (wave-local), vf from V-LDS ----
    f32x4 ov[4];
#pragma unroll
    for (int nt = 0; nt < 4; ++nt) ov[nt] = (f32x4){0.f, 0.f, 0.f, 0.f};
#pragma unroll
    for (int ks = 0; ks < 8; ++ks) {
        f16x8 pa = *(const f16x8*)&KP[(w * 16 + c) * 264 + ks * 32 + q * 8];
#pragma unroll
        for (int nt = 0; nt < 4; ++nt) {
            int chunk = ks * 4 + q;
            int chs = (chunk & 24) | ((chunk & 7) ^ (c & 7));
            f16x8 vf = *(const f16x8*)&Vl[(nt * 16 + c) * 256 + chs * 8];
            ov[nt] = __builtin_amdgcn_mfma_f32_16x16x32_f16(pa, vf, ov[nt], 0, 0, 0);
        }
    }

    // ---- out via QO (wave-local rows), coalesced 16B stores ----
#pragma unroll
    for (int nt = 0; nt < 4; ++nt)
#pragma unroll
        for (int r = 0; r < 4; ++r)
            QO[w * 16 + q * 4 + r][nt * 16 + c] = f2h(ov[nt][r]);

#pragma unroll
    for (int pass = 0; pass < 2; ++pass) {
        int lr  = w * 16 + pass * 8 + (lane >> 3);
        int col = (lane & 7) * 8;
        uint4 vv = *(uint4*)&QO[lr][col];
        *(uint4*)(AO + ((size_t)b * SEQ + n0 + lr) * DMODEL + h * DK + col) = vv;
    }
}

// ---------------------------------------------------------------------------
// Kernel 3 (proven): Out[16384][1024] = AO(f16) @ WoT^T(f16) + bo.
// ---------------------------------------------------------------------------
#define OBM 128
#define OBN 128
#define OBK 64

__global__ __launch_bounds__(256) void out_gemm_mfma(
    const u16* __restrict__ AO, const u16* __restrict__ WoT,
    const float* __restrict__ bo, float* __restrict__ Out)
{
    const int c0 = blockIdx.x * OBN;
    const int r0 = blockIdx.y * OBM;
    const int t  = threadIdx.x;
    const int lane = t & 63;
    const int w  = t >> 6;
    const int wr = w >> 1, wc = w & 1;
    const int q  = lane >> 4, c = lane & 15;

    __shared__ u16 As[OBM * OBK];
    __shared__ u16 Bs[OBN * OBK];

    f32x4 acc[4][4];
#pragma unroll
    for (int m = 0; m < 4; ++m)
#pragma unroll
        for (int n = 0; n < 4; ++n) acc[m][n] = (f32x4){0.f, 0.f, 0.f, 0.f};

    for (int k0 = 0; k0 < DMODEL; k0 += OBK) {
#pragma unroll
        for (int i = 0; i < 4; ++i) {
            int li  = i * 256 + t;
            int row = li >> 3;
            int c8  = (li & 7) ^ (row & 7);
            gl2lds16(AO  + (size_t)(r0 + row) * DMODEL + k0 + c8 * 8, (u16*)As + (size_t)li * 8);
            gl2lds16(WoT + (size_t)(c0 + row) * DMODEL + k0 + c8 * 8, (u16*)Bs + (size_t)li * 8);
        }
        __syncthreads();

#pragma unroll
        for (int s = 0; s < 2; ++s) {
            f16x8 af[4], bf[4];
#pragma unroll
            for (int m = 0; m < 4; ++m) {
                int row = wr * 64 + m * 16 + c;
                int c8  = (s * 4 + q) ^ (row & 7);
                af[m] = *(const f16x8*)&As[row * 64 + c8 * 8];
            }
#pragma unroll
            for (int n = 0; n < 4; ++n) {
                int row = wc * 64 + n * 16 + c;
                int c8  = (s * 4 + q) ^ (row & 7);
                bf[n] = *(const f16x8*)&Bs[row * 64 + c8 * 8];
            }
#pragma unroll
            for (int m = 0; m < 4; ++m)
#pragma unroll
                for (int n = 0; n < 4; ++n)
                    acc[m][n] = __builtin_amdgcn_mfma_f32_16x16x32_f16(af[m], bf[n], acc[m][n], 0, 0, 0);
        }
        __syncthreads();
    }

    float bv[4];
#pragma unroll
    for (int n = 0; n < 4; ++n) bv[n] = bo[c0 + wc * 64 + n * 16 + c];
#pragma unroll
    for (int m = 0; m < 4; ++m) {
        int rowb = r0 + wr * 64 + m * 16 + q * 4;
#pragma unroll
        for (int r = 0; r < 4; ++r) {
            float* dst = Out + (size_t)(rowb + r) * DMODEL + c0 + wc * 64 + c;
#pragma unroll
            for (int n = 0; n < 4; ++n) dst[n * 16] = acc[m][n][r] + bv[n];
        }
    }
}

// ---------------------------------------------------------------------------
extern "C" void kernel_launch(void* const* d_in, const int* in_sizes, int n_in,
                              void* d_out, int out_size, void* d_ws, size_t ws_size,
                              hipStream_t stream)
{
    const float* K   = (const float*)d_in[0];
    const float* Q   = (const float*)d_in[1];
    const float* V   = (const float*)d_in[2];
    const float* We  = (const float*)d_in[3];
    const float* be  = (const float*)d_in[4];
    const float* Wf  = (const float*)d_in[5];
    const float* bfp = (const float*)d_in[6];
    const float* Wo  = (const float*)d_in[7];
    const float* bo  = (const float*)d_in[8];
    float* Out = (float*)d_out;

    const size_t M1 = 1048576;           // 1M u16 = 2MB
    const size_t TB = (size_t)BB * DMODEL * SEQ;   // 16.78M u16 = 33.5MB

    if (ws_size >= 2 * (4 * M1 + 2 * TB)) {
        // ---- parallel layout (72MB): KpF|VpF|WeT|WfT|KT|VT ; AO=KT, WoT=WeT
        u16* KpF = (u16*)d_ws;
        u16* VpF = KpF + M1;
        u16* WeT = VpF + M1;
        u16* WfT = WeT + M1;
        u16* KT  = WfT + M1;
        u16* VT  = KT + TB;
        u16* AO  = KT;                   // alias: KT dead after proj
        u16* WoT = WeT;                  // alias: WeT dead after proj

        tconv<<<dim3(SEQ / 64, LK / 64, 1), 256, 0, stream>>>(We, WeT, LK, SEQ, 0, 0);
        tconv<<<dim3(SEQ / 64, LK / 64, 1), 256, 0, stream>>>(Wf, WfT, LK, SEQ, 0, 0);
        tconv<<<dim3(SEQ / 64, DMODEL / 64, BB), 256, 0, stream>>>(
            K, KT, DMODEL, SEQ, (size_t)SEQ * DMODEL, (size_t)DMODEL * SEQ);
        tconv<<<dim3(SEQ / 64, DMODEL / 64, BB), 256, 0, stream>>>(
            V, VT, DMODEL, SEQ, (size_t)SEQ * DMODEL, (size_t)DMODEL * SEQ);
        proj_both<<<dim3(128), 256, 0, stream>>>(WeT, WfT, KT, VT, be, bfp, KpF, VpF);
        wo_convert<<<dim3(DMODEL / 64, DMODEL / 64), 256, 0, stream>>>(Wo, WoT);
        attn_mfma<<<dim3(SEQ / 64, BH), 256, 0, stream>>>(Q, KpF, VpF, AO);
        out_gemm_mfma<<<dim3(DMODEL / OBN, (BB * SEQ) / OBM), 256, 0, stream>>>(AO, WoT, bo, Out);
    } else {
        // ---- serial fallback == exact R11 layout (39.5MB proven) ----
        u16* KpF = (u16*)d_ws;
        u16* VpF = KpF + (size_t)BB * LK * DMODEL;
        u16* BIG = VpF + (size_t)BB * DMODEL * LK;
        u16* Wsm = BIG + (size_t)BB * SEQ * DMODEL;

        tconv<<<dim3(SEQ / 64, LK / 64, 1), 256, 0, stream>>>(We, Wsm, LK, SEQ, 0, 0);
        tconv<<<dim3(SEQ / 64, DMODEL / 64, BB), 256, 0, stream>>>(
            K, BIG, DMODEL, SEQ, (size_t)SEQ * DMODEL, (size_t)DMODEL * SEQ);
        proj_gemm<<<dim3(DMODEL / 128, LK / 128, BB), 256, 0, stream>>>(
            Wsm, BIG, be, KpF, 1, (size_t)0, (size_t)DMODEL * SEQ, DMODEL, (size_t)LK * DMODEL);
        tconv<<<dim3(SEQ / 64, LK / 64, 1), 256, 0, stream>>>(Wf, Wsm, LK, SEQ, 0, 0);
        tconv<<<dim3(SEQ / 64, DMODEL / 64, BB), 256, 0, stream>>>(
            V, BIG, DMODEL, SEQ, (size_t)SEQ * DMODEL, (size_t)DMODEL * SEQ);
        proj_gemm<<<dim3(LK / 128, DMODEL / 128, BB), 256, 0, stream>>>(
            BIG, Wsm, bfp, VpF, 0, (size_t)DMODEL * SEQ, (size_t)0, LK, (size_t)DMODEL * LK);
        wo_convert<<<dim3(DMODEL / 64, DMODEL / 64), 256, 0, stream>>>(Wo, Wsm);
        attn_mfma<<<dim3(SEQ / 64, BH), 256, 0, stream>>>(Q, KpF, VpF, BIG);
        out_gemm_mfma<<<dim3(DMODEL / OBN, (BB * SEQ) / OBM), 256, 0, stream>>>(BIG, Wsm, bo, Out);
    }
}

// Round 8
// 379.558 us; speedup vs baseline: 1.6523x; 1.0419x over previous
//
#include <hip/hip_runtime.h>
#include <hip/hip_bf16.h>

// R13: attn rewritten as persistent-K/V blocks: grid (4, BH)=256 blocks
//      (1/CU), 512 threads (8 waves). Stage K/V ONCE per (b,h) (R12-verified
//      swizzles), then 8 barrier-free passes of 128 Q-rows: Q direct to regs
//      (prefetched), P/out-bounce wave-local [128][264]. Kills the 64x
//      redundant K/V staging + per-block latency chains (R12: 10us/block
//      stall-dominated). proj/out/tconv unchanged from R12.
#define BB      4
#define SEQ     4096
#define DMODEL  1024
#define NHEAD   16
#define DK      64
#define LK      256
#define BH      (BB*NHEAD)   // 64

typedef unsigned short u16;
typedef unsigned int   u32;
typedef float f32x4  __attribute__((ext_vector_type(4)));
typedef _Float16 f16x8 __attribute__((ext_vector_type(8)));

__device__ __forceinline__ u16 f2h(float f) {
    _Float16 h = (_Float16)f;                 // v_cvt_f16_f32, RNE
    u16 r; __builtin_memcpy(&r, &h, 2); return r;
}
__device__ __forceinline__ u32 packh(float a, float b) {
    return (u32)f2h(a) | ((u32)f2h(b) << 16);
}
__device__ __forceinline__ f16x8 pack8h(float4 a, float4 b) {
    union { uint4 u; f16x8 h; } r;
    r.u = make_uint4(packh(a.x, a.y), packh(a.z, a.w),
                     packh(b.x, b.y), packh(b.z, b.w));
    return r.h;
}
// async global->LDS, 16B per lane (dest must be wave-uniform base + lane*16)
__device__ __forceinline__ void gl2lds16(const void* g, void* l) {
    __builtin_amdgcn_global_load_lds(
        (const __attribute__((address_space(1))) unsigned int*)g,
        (__attribute__((address_space(3))) unsigned int*)l,
        16, 0, 0);
}

// ---------------------------------------------------------------------------
// Kernel 0: generic transpose+convert, f32 [R][C] -> f16 [C][R].
// ---------------------------------------------------------------------------
__global__ __launch_bounds__(256) void tconv(
    const float* __restrict__ src, u16* __restrict__ dst,
    int ss, int ds, size_t sbo, size_t dbo)
{
    const float* S = src + (size_t)blockIdx.z * sbo;
    u16* D         = dst + (size_t)blockIdx.z * dbo;
    const int r0 = blockIdx.x * 64;   // src rows
    const int c0 = blockIdx.y * 64;   // src cols
    __shared__ float T[64][65];
    const int t = threadIdx.x;
    {
        int rr = (t >> 4) * 4;
        int cc = (t & 15) * 4;
#pragma unroll
        for (int i = 0; i < 4; ++i) {
            float4 v = *(const float4*)(S + (size_t)(r0 + rr + i) * ss + c0 + cc);
            T[rr + i][cc + 0] = v.x; T[rr + i][cc + 1] = v.y;
            T[rr + i][cc + 2] = v.z; T[rr + i][cc + 3] = v.w;
        }
    }
    __syncthreads();
    int cr = t >> 2, rc = (t & 3) * 16;
    u32 o[8];
#pragma unroll
    for (int j = 0; j < 8; ++j)
        o[j] = packh(T[rc + 2 * j][cr], T[rc + 2 * j + 1][cr]);
    u16* d = D + (size_t)(c0 + cr) * ds + r0 + rc;
    *(uint4*)(d)     = make_uint4(o[0], o[1], o[2], o[3]);
    *(uint4*)(d + 8) = make_uint4(o[4], o[5], o[6], o[7]);
}

// ---------------------------------------------------------------------------
// Kernel 3a (proven): WoT[j][k] fp16 = Wo[k][j] f32.
// ---------------------------------------------------------------------------
__global__ __launch_bounds__(256) void wo_convert(
    const float* __restrict__ Wo, u16* __restrict__ WoT)
{
    const int n0 = blockIdx.x * 64, k0 = blockIdx.y * 64;
    __shared__ float T[64][65];
    const int t = threadIdx.x;
    {
        int kr = (t >> 4) * 4;
        int nc = (t & 15) * 4;
#pragma unroll
        for (int i = 0; i < 4; ++i) {
            float4 v = *(const float4*)(Wo + (size_t)(k0 + kr + i) * DMODEL + n0 + nc);
            T[kr + i][nc + 0] = v.x; T[kr + i][nc + 1] = v.y;
            T[kr + i][nc + 2] = v.z; T[kr + i][nc + 3] = v.w;
        }
    }
    __syncthreads();
    int n = t >> 2, kc = (t & 3) * 16;
    u32 o[8];
#pragma unroll
    for (int j = 0; j < 8; ++j)
        o[j] = packh(T[kc + j * 2][n], T[kc + j * 2 + 1][n]);
    u16* dst = WoT + (size_t)(n0 + n) * DMODEL + k0 + kc;
    *(uint4*)(dst)     = make_uint4(o[0], o[1], o[2], o[3]);
    *(uint4*)(dst + 8) = make_uint4(o[4], o[5], o[6], o[7]);
}

// ---------------------------------------------------------------------------
// proj_gemm / proj_both (R11/R12-proven): batched TN GEMM, dbuf.
// ---------------------------------------------------------------------------
#define PROJ_BODY(Ab, Bb, bias, Cb, bias_on_row, c_row_stride, c0, r0)          \
    const int t  = threadIdx.x;                                                 \
    const int lane = t & 63;                                                    \
    const int w  = t >> 6;                                                      \
    const int wr = w >> 1, wc = w & 1;                                          \
    const int q  = lane >> 4, c = lane & 15;                                    \
    __shared__ u16 As[2][128 * 64];                                             \
    __shared__ u16 Bs[2][128 * 64];                                             \
    auto stage = [&](int buf, int kk) {                                         \
        _Pragma("unroll")                                                       \
        for (int i = 0; i < 4; ++i) {                                           \
            int li  = i * 256 + t;                                              \
            int row = li >> 3;                                                  \
            int c8  = (li & 7) ^ (row & 7);                                     \
            gl2lds16(Ab + (size_t)(r0 + row) * SEQ + kk + c8 * 8, &As[buf][(size_t)li * 8]); \
            gl2lds16(Bb + (size_t)(c0 + row) * SEQ + kk + c8 * 8, &Bs[buf][(size_t)li * 8]); \
        }                                                                       \
    };                                                                          \
    f32x4 acc[4][4];                                                            \
    _Pragma("unroll")                                                           \
    for (int m = 0; m < 4; ++m)                                                 \
        _Pragma("unroll")                                                       \
        for (int n = 0; n < 4; ++n) acc[m][n] = (f32x4){0.f, 0.f, 0.f, 0.f};    \
    stage(0, 0);                                                                \
    __syncthreads();                                                            \
    int cur = 0;                                                                \
    for (int k0 = 0; k0 < SEQ; k0 += 64) {                                      \
        if (k0 + 64 < SEQ) stage(cur ^ 1, k0 + 64);                             \
        _Pragma("unroll")                                                       \
        for (int s = 0; s < 2; ++s) {                                           \
            f16x8 af[4], bf[4];                                                 \
            _Pragma("unroll")                                                   \
            for (int m = 0; m < 4; ++m) {                                       \
                int row = wr * 64 + m * 16 + c;                                 \
                int c8  = (s * 4 + q) ^ (row & 7);                              \
                af[m] = *(const f16x8*)&As[cur][row * 64 + c8 * 8];             \
            }                                                                   \
            _Pragma("unroll")                                                   \
            for (int n = 0; n < 4; ++n) {                                       \
                int row = wc * 64 + n * 16 + c;                                 \
                int c8  = (s * 4 + q) ^ (row & 7);                              \
                bf[n] = *(const f16x8*)&Bs[cur][row * 64 + c8 * 8];             \
            }                                                                   \
            _Pragma("unroll")                                                   \
            for (int m = 0; m < 4; ++m)                                         \
                _Pragma("unroll")                                               \
                for (int n = 0; n < 4; ++n)                                     \
                    acc[m][n] = __builtin_amdgcn_mfma_f32_16x16x32_f16(af[m], bf[n], acc[m][n], 0, 0, 0); \
        }                                                                       \
        __syncthreads();                                                        \
        cur ^= 1;                                                               \
    }                                                                           \
    if (bias_on_row) {                                                          \
        _Pragma("unroll")                                                       \
        for (int m = 0; m < 4; ++m) {                                           \
            int rowb = r0 + wr * 64 + m * 16 + q * 4;                           \
            _Pragma("unroll")                                                   \
            for (int r = 0; r < 4; ++r) {                                       \
                float bv = bias[rowb + r];                                      \
                u16* dst = Cb + (size_t)(rowb + r) * c_row_stride + c0 + wc * 64 + c; \
                _Pragma("unroll")                                               \
                for (int n = 0; n < 4; ++n) dst[n * 16] = f2h(acc[m][n][r] + bv); \
            }                                                                   \
        }                                                                       \
    } else {                                                                    \
        float bv[4];                                                            \
        _Pragma("unroll")                                                       \
        for (int n = 0; n < 4; ++n) bv[n] = bias[c0 + wc * 64 + n * 16 + c];    \
        _Pragma("unroll")                                                       \
        for (int m = 0; m < 4; ++m) {                                           \
            int rowb = r0 + wr * 64 + m * 16 + q * 4;                           \
            _Pragma("unroll")                                                   \
            for (int r = 0; r < 4; ++r) {                                       \
                u16* dst = Cb + (size_t)(rowb + r) * c_row_stride + c0 + wc * 64 + c; \
                _Pragma("unroll")                                               \
                for (int n = 0; n < 4; ++n) dst[n * 16] = f2h(acc[m][n][r] + bv[n]); \
            }                                                                   \
        }                                                                       \
    }

__global__ __launch_bounds__(256) void proj_gemm(
    const u16* __restrict__ A, const u16* __restrict__ B,
    const float* __restrict__ bias, u16* __restrict__ Cout,
    int bias_on_row, size_t a_batch, size_t b_batch,
    int c_row_stride, size_t c_batch)
{
    const u16* Ab = A + (size_t)blockIdx.z * a_batch;
    const u16* Bb = B + (size_t)blockIdx.z * b_batch;
    u16* Cb       = Cout + (size_t)blockIdx.z * c_batch;
    const int c0 = blockIdx.x * 128;
    const int r0 = blockIdx.y * 128;
    PROJ_BODY(Ab, Bb, bias, Cb, bias_on_row, c_row_stride, c0, r0)
}

__global__ __launch_bounds__(256) void proj_both(
    const u16* __restrict__ WeT, const u16* __restrict__ WfT,
    const u16* __restrict__ KT,  const u16* __restrict__ VT,
    const float* __restrict__ be, const float* __restrict__ bfp,
    u16* __restrict__ KpF, u16* __restrict__ VpF)
{
    const int id = blockIdx.x;
    const u16 *Ab, *Bb; const float* bias; u16* Cb;
    int bias_on_row, c_row_stride, c0, r0;
    if (id < 64) {              // K-proj: C[lk][dm] = WeT @ KT[b]^T + be[lk]
        int b = id >> 4, s = id & 15;
        c0 = (s & 7) * 128; r0 = (s >> 3) * 128;
        Ab = WeT; Bb = KT + (size_t)b * DMODEL * SEQ;
        bias = be; bias_on_row = 1;
        Cb = KpF + (size_t)b * LK * DMODEL; c_row_stride = DMODEL;
    } else {                    // V-proj: C[dm][lk] = VT[b] @ WfT^T + bf[lk]
        int j = id - 64, b = j >> 4, s = j & 15;
        c0 = (s & 1) * 128; r0 = (s >> 1) * 128;
        Ab = VT + (size_t)b * DMODEL * SEQ; Bb = WfT;
        bias = bfp; bias_on_row = 0;
        Cb = VpF + (size_t)b * DMODEL * LK; c_row_stride = LK;
    }
    PROJ_BODY(Ab, Bb, bias, Cb, bias_on_row, c_row_stride, c0, r0)
}

// ---------------------------------------------------------------------------
// Kernel 2 (R13): persistent-K/V fused attn.
// Grid (4, BH) = 256 blocks, 512 threads (8 waves, 2/SIMD).
// Stage K [256][64] + V [64][256] once (R12-verified swizzles); one barrier;
// then 8 passes x 128 Q-rows, barrier-free: Q direct-to-reg (prefetched),
// QK^T from K-LDS, reg softmax, P -> wave-local rows of Pl[128][264],
// PV from V-LDS, out via wave-local Pl bounce (P dead after PV).
// ---------------------------------------------------------------------------
__global__ __launch_bounds__(512) void attn_mfma(
    const float* __restrict__ Qin, const u16* __restrict__ KpF,
    const u16* __restrict__ VpF,   u16* __restrict__ AO)
{
    const int bh = blockIdx.y, b = bh >> 4, h = bh & 15;
    const int n0 = blockIdx.x * 1024;
    const int t  = threadIdx.x;
    const int w    = t >> 6;          // wave 0..7
    const int lane = t & 63;
    const int q    = lane >> 4;       // quad 0..3
    const int c    = lane & 15;

    __shared__ u16 Kl[16384];         // K [256][64], chunk ^ (row&7)
    __shared__ u16 Vl[16384];         // V [64][256], low-3 chunk bits ^ (row&7)
    __shared__ u16 Pl[128 * 264];     // P / out bounce, wave-local rows

    // ---- stage K (2048 x 16B chunks over 512 threads) ----
    const u16* kbase = KpF + (size_t)b * LK * DMODEL + h * DK;
#pragma unroll
    for (int i = 0; i < 4; ++i) {
        int li = i * 512 + t;
        int row = li >> 3, ch = li & 7;
        int chs = ch ^ (row & 7);
        gl2lds16(kbase + (size_t)row * DMODEL + chs * 8, Kl + (size_t)li * 8);
    }
    // ---- stage V ----
    const u16* vbase = VpF + ((size_t)b * DMODEL + h * DK) * LK;
#pragma unroll
    for (int i = 0; i < 4; ++i) {
        int li = i * 512 + t;
        int row = li >> 5, ch = li & 31;
        int chs = (ch & 24) | ((ch & 7) ^ (row & 7));
        gl2lds16(vbase + (size_t)row * LK + chs * 8, Vl + (size_t)li * 8);
    }
    __syncthreads();   // ONLY barrier: K/V ready; everything after is wave-local

    // ---- per-lane Q base: row (n0 + p*128 + w*16 + c), cols h*64.. ----
    const float* qbase = Qin + ((size_t)b * SEQ + n0 + w * 16 + c) * DMODEL + h * DK;
    const float4* qp0 = (const float4*)qbase;
    float4 q0 = qp0[2 * q], q1 = qp0[2 * q + 1];
    float4 q2 = qp0[8 + 2 * q], q3 = qp0[8 + 2 * q + 1];

    for (int p = 0; p < 8; ++p) {
        // convert current Q to A-frags, then prefetch next pass's Q
        f16x8 a0 = pack8h(q0, q1);
        f16x8 a1 = pack8h(q2, q3);
        if (p < 7) {
            const float4* qp = (const float4*)(qbase + (size_t)(p + 1) * 128 * DMODEL);
            q0 = qp[2 * q]; q1 = qp[2 * q + 1];
            q2 = qp[8 + 2 * q]; q3 = qp[8 + 2 * q + 1];
        }

        // ---- scores from K-LDS ----
        f32x4 sc[16];
#pragma unroll
        for (int nt = 0; nt < 16; ++nt) sc[nt] = (f32x4){0.f, 0.f, 0.f, 0.f};
#pragma unroll
        for (int nt = 0; nt < 16; ++nt) {
            int ra = (nt * 16 + c) * 64;
            f16x8 b0 = *(const f16x8*)&Kl[ra + ((q ^ (c & 7)) * 8)];
            f16x8 b1 = *(const f16x8*)&Kl[ra + (((4 + q) ^ (c & 7)) * 8)];
            sc[nt] = __builtin_amdgcn_mfma_f32_16x16x32_f16(a0, b0, sc[nt], 0, 0, 0);
            sc[nt] = __builtin_amdgcn_mfma_f32_16x16x32_f16(a1, b1, sc[nt], 0, 0, 0);
        }

        // ---- softmax over 256 cols, in registers ----
        float mx[4] = {-1e30f, -1e30f, -1e30f, -1e30f};
#pragma unroll
        for (int nt = 0; nt < 16; ++nt) {
            sc[nt] *= 0.125f;   // 1/sqrt(DK)
#pragma unroll
            for (int r = 0; r < 4; ++r) mx[r] = fmaxf(mx[r], sc[nt][r]);
        }
#pragma unroll
        for (int d = 1; d < 16; d <<= 1)
#pragma unroll
            for (int r = 0; r < 4; ++r) mx[r] = fmaxf(mx[r], __shfl_xor(mx[r], d, 64));

        float sm[4] = {0.f, 0.f, 0.f, 0.f};
#pragma unroll
        for (int nt = 0; nt < 16; ++nt)
#pragma unroll
            for (int r = 0; r < 4; ++r) {
                float e = __expf(sc[nt][r] - mx[r]);
                sc[nt][r] = e;
                sm[r] += e;
            }
#pragma unroll
        for (int d = 1; d < 16; d <<= 1)
#pragma unroll
            for (int r = 0; r < 4; ++r) sm[r] += __shfl_xor(sm[r], d, 64);
        float inv[4];
#pragma unroll
        for (int r = 0; r < 4; ++r) inv[r] = 1.0f / sm[r];

        // ---- P -> wave-local rows of Pl (stride 264) ----
#pragma unroll
        for (int nt = 0; nt < 16; ++nt)
#pragma unroll
            for (int r = 0; r < 4; ++r)
                Pl[(w * 16 + q * 4 + r) * 264 + nt * 16 + c] = f2h(sc[nt][r] * inv[r]);

        // ---- PV: pa from Pl (wave-local), vf from V-LDS ----
        f32x4 ov[4];
#pragma unroll
        for (int nt = 0; nt < 4; ++nt) ov[nt] = (f32x4){0.f, 0.f, 0.f, 0.f};
#pragma unroll
        for (int ks = 0; ks < 8; ++ks) {
            f16x8 pa = *(const f16x8*)&Pl[(w * 16 + c) * 264 + ks * 32 + q * 8];
#pragma unroll
            for (int nt = 0; nt < 4; ++nt) {
                int chunk = ks * 4 + q;
                int chs = (chunk & 24) | ((chunk & 7) ^ (c & 7));
                f16x8 vf = *(const f16x8*)&Vl[(nt * 16 + c) * 256 + chs * 8];
                ov[nt] = __builtin_amdgcn_mfma_f32_16x16x32_f16(pa, vf, ov[nt], 0, 0, 0);
            }
        }

        // ---- out: bounce through wave-local Pl rows (P dead), 16B stores ----
#pragma unroll
        for (int nt = 0; nt < 4; ++nt)
#pragma unroll
            for (int r = 0; r < 4; ++r)
                Pl[(w * 16 + q * 4 + r) * 264 + nt * 16 + c] = f2h(ov[nt][r]);

#pragma unroll
        for (int ps = 0; ps < 2; ++ps) {
            int lr  = w * 16 + ps * 8 + (lane >> 3);
            int col = (lane & 7) * 8;
            uint4 vv = *(uint4*)&Pl[lr * 264 + col];
            *(uint4*)(AO + ((size_t)b * SEQ + n0 + p * 128 + lr) * DMODEL + h * DK + col) = vv;
        }
    }
}

// ---------------------------------------------------------------------------
// Kernel 3 (proven): Out[16384][1024] = AO(f16) @ WoT^T(f16) + bo.
// ---------------------------------------------------------------------------
#define OBM 128
#define OBN 128
#define OBK 64

__global__ __launch_bounds__(256) void out_gemm_mfma(
    const u16* __restrict__ AO, const u16* __restrict__ WoT,
    const float* __restrict__ bo, float* __restrict__ Out)
{
    const int c0 = blockIdx.x * OBN;
    const int r0 = blockIdx.y * OBM;
    const int t  = threadIdx.x;
    const int lane = t & 63;
    const int w  = t >> 6;
    const int wr = w >> 1, wc = w & 1;
    const int q  = lane >> 4, c = lane & 15;

    __shared__ u16 As[OBM * OBK];
    __shared__ u16 Bs[OBN * OBK];

    f32x4 acc[4][4];
#pragma unroll
    for (int m = 0; m < 4; ++m)
#pragma unroll
        for (int n = 0; n < 4; ++n) acc[m][n] = (f32x4){0.f, 0.f, 0.f, 0.f};

    for (int k0 = 0; k0 < DMODEL; k0 += OBK) {
#pragma unroll
        for (int i = 0; i < 4; ++i) {
            int li  = i * 256 + t;
            int row = li >> 3;
            int c8  = (li & 7) ^ (row & 7);
            gl2lds16(AO  + (size_t)(r0 + row) * DMODEL + k0 + c8 * 8, (u16*)As + (size_t)li * 8);
            gl2lds16(WoT + (size_t)(c0 + row) * DMODEL + k0 + c8 * 8, (u16*)Bs + (size_t)li * 8);
        }
        __syncthreads();

#pragma unroll
        for (int s = 0; s < 2; ++s) {
            f16x8 af[4], bf[4];
#pragma unroll
            for (int m = 0; m < 4; ++m) {
                int row = wr * 64 + m * 16 + c;
                int c8  = (s * 4 + q) ^ (row & 7);
                af[m] = *(const f16x8*)&As[row * 64 + c8 * 8];
            }
#pragma unroll
            for (int n = 0; n < 4; ++n) {
                int row = wc * 64 + n * 16 + c;
                int c8  = (s * 4 + q) ^ (row & 7);
                bf[n] = *(const f16x8*)&Bs[row * 64 + c8 * 8];
            }
#pragma unroll
            for (int m = 0; m < 4; ++m)
#pragma unroll
                for (int n = 0; n < 4; ++n)
                    acc[m][n] = __builtin_amdgcn_mfma_f32_16x16x32_f16(af[m], bf[n], acc[m][n], 0, 0, 0);
        }
        __syncthreads();
    }

    float bv[4];
#pragma unroll
    for (int n = 0; n < 4; ++n) bv[n] = bo[c0 + wc * 64 + n * 16 + c];
#pragma unroll
    for (int m = 0; m < 4; ++m) {
        int rowb = r0 + wr * 64 + m * 16 + q * 4;
#pragma unroll
        for (int r = 0; r < 4; ++r) {
            float* dst = Out + (size_t)(rowb + r) * DMODEL + c0 + wc * 64 + c;
#pragma unroll
            for (int n = 0; n < 4; ++n) dst[n * 16] = acc[m][n][r] + bv[n];
        }
    }
}

// ---------------------------------------------------------------------------
extern "C" void kernel_launch(void* const* d_in, const int* in_sizes, int n_in,
                              void* d_out, int out_size, void* d_ws, size_t ws_size,
                              hipStream_t stream)
{
    const float* K   = (const float*)d_in[0];
    const float* Q   = (const float*)d_in[1];
    const float* V   = (const float*)d_in[2];
    const float* We  = (const float*)d_in[3];
    const float* be  = (const float*)d_in[4];
    const float* Wf  = (const float*)d_in[5];
    const float* bfp = (const float*)d_in[6];
    const float* Wo  = (const float*)d_in[7];
    const float* bo  = (const float*)d_in[8];
    float* Out = (float*)d_out;

    const size_t M1 = 1048576;           // 1M u16 = 2MB
    const size_t TB = (size_t)BB * DMODEL * SEQ;   // 16.78M u16 = 33.5MB

    if (ws_size >= 2 * (4 * M1 + 2 * TB)) {
        // ---- parallel layout (72MB): KpF|VpF|WeT|WfT|KT|VT ; AO=KT, WoT=WeT
        u16* KpF = (u16*)d_ws;
        u16* VpF = KpF + M1;
        u16* WeT = VpF + M1;
        u16* WfT = WeT + M1;
        u16* KT  = WfT + M1;
        u16* VT  = KT + TB;
        u16* AO  = KT;                   // alias: KT dead after proj
        u16* WoT = WeT;                  // alias: WeT dead after proj

        tconv<<<dim3(SEQ / 64, LK / 64, 1), 256, 0, stream>>>(We, WeT, LK, SEQ, 0, 0);
        tconv<<<dim3(SEQ / 64, LK / 64, 1), 256, 0, stream>>>(Wf, WfT, LK, SEQ, 0, 0);
        tconv<<<dim3(SEQ / 64, DMODEL / 64, BB), 256, 0, stream>>>(
            K, KT, DMODEL, SEQ, (size_t)SEQ * DMODEL, (size_t)DMODEL * SEQ);
        tconv<<<dim3(SEQ / 64, DMODEL / 64, BB), 256, 0, stream>>>(
            V, VT, DMODEL, SEQ, (size_t)SEQ * DMODEL, (size_t)DMODEL * SEQ);
        proj_both<<<dim3(128), 256, 0, stream>>>(WeT, WfT, KT, VT, be, bfp, KpF, VpF);
        wo_convert<<<dim3(DMODEL / 64, DMODEL / 64), 256, 0, stream>>>(Wo, WoT);
        attn_mfma<<<dim3(4, BH), 512, 0, stream>>>(Q, KpF, VpF, AO);
        out_gemm_mfma<<<dim3(DMODEL / OBN, (BB * SEQ) / OBM), 256, 0, stream>>>(AO, WoT, bo, Out);
    } else {
        // ---- serial fallback == exact R11 layout (39.5MB proven) ----
        u16* KpF = (u16*)d_ws;
        u16* VpF = KpF + (size_t)BB * LK * DMODEL;
        u16* BIG = VpF + (size_t)BB * DMODEL * LK;
        u16* Wsm = BIG + (size_t)BB * SEQ * DMODEL;

        tconv<<<dim3(SEQ / 64, LK / 64, 1), 256, 0, stream>>>(We, Wsm, LK, SEQ, 0, 0);
        tconv<<<dim3(SEQ / 64, DMODEL / 64, BB), 256, 0, stream>>>(
            K, BIG, DMODEL, SEQ, (size_t)SEQ * DMODEL, (size_t)DMODEL * SEQ);
        proj_gemm<<<dim3(DMODEL / 128, LK / 128, BB), 256, 0, stream>>>(
            Wsm, BIG, be, KpF, 1, (size_t)0, (size_t)DMODEL * SEQ, DMODEL, (size_t)LK * DMODEL);
        tconv<<<dim3(SEQ / 64, LK / 64, 1), 256, 0, stream>>>(Wf, Wsm, LK, SEQ, 0, 0);
        tconv<<<dim3(SEQ / 64, DMODEL / 64, BB), 256, 0, stream>>>(
            V, BIG, DMODEL, SEQ, (size_t)SEQ * DMODEL, (size_t)DMODEL * SEQ);
        proj_gemm<<<dim3(LK / 128, DMODEL / 128, BB), 256, 0, stream>>>(
            BIG, Wsm, bfp, VpF, 0, (size_t)DMODEL * SEQ, (size_t)0, LK, (size_t)DMODEL * LK);
        wo_convert<<<dim3(DMODEL / 64, DMODEL / 64), 256, 0, stream>>>(Wo, Wsm);
        attn_mfma<<<dim3(4, BH), 512, 0, stream>>>(Q, KpF, VpF, BIG);
        out_gemm_mfma<<<dim3(DMODEL / OBN, (BB * SEQ) / OBM), 256, 0, stream>>>(BIG, Wsm, bo, Out);
    }
}

// Round 9
// 337.533 us; speedup vs baseline: 1.8580x; 1.1245x over previous
//
#include <hip/hip_runtime.h>
#include <hip/hip_bf16.h>

// R14: (1) split-K proj (SPLITK=4, 512 blocks=2/CU, f32 partials + fused
//      reduce) -- fixes proj_both's 5% occupancy / half-idle machine;
//      ws-gated (~111MB) with full fallback to R13 (75.5MB) / R11-serial.
//      (2) tconv_all: 5 prep launches merged into 1 (launch-gap savings).
//      (3) bijective XCD swizzles on out_gemm + attn grids (L2 locality).
#define BB      4
#define SEQ     4096
#define DMODEL  1024
#define NHEAD   16
#define DK      64
#define LK      256
#define BH      (BB*NHEAD)   // 64
#define SPLITK  4

typedef unsigned short u16;
typedef unsigned int   u32;
typedef float f32x4  __attribute__((ext_vector_type(4)));
typedef _Float16 f16x8 __attribute__((ext_vector_type(8)));

__device__ __forceinline__ u16 f2h(float f) {
    _Float16 h = (_Float16)f;                 // v_cvt_f16_f32, RNE
    u16 r; __builtin_memcpy(&r, &h, 2); return r;
}
__device__ __forceinline__ u32 packh(float a, float b) {
    return (u32)f2h(a) | ((u32)f2h(b) << 16);
}
__device__ __forceinline__ f16x8 pack8h(float4 a, float4 b) {
    union { uint4 u; f16x8 h; } r;
    r.u = make_uint4(packh(a.x, a.y), packh(a.z, a.w),
                     packh(b.x, b.y), packh(b.z, b.w));
    return r.h;
}
// async global->LDS, 16B per lane (dest must be wave-uniform base + lane*16)
__device__ __forceinline__ void gl2lds16(const void* g, void* l) {
    __builtin_amdgcn_global_load_lds(
        (const __attribute__((address_space(1))) unsigned int*)g,
        (__attribute__((address_space(3))) unsigned int*)l,
        16, 0, 0);
}

// ---------------------------------------------------------------------------
// tconv body (proven): f32 [R][C] tile -> f16 [C][R] tile via LDS transpose.
// ---------------------------------------------------------------------------
__device__ __forceinline__ void tconv_body(
    const float* __restrict__ S, u16* __restrict__ D,
    int ss, int ds, int r0, int c0, int t)
{
    __shared__ float T[64][65];
    {
        int rr = (t >> 4) * 4;
        int cc = (t & 15) * 4;
#pragma unroll
        for (int i = 0; i < 4; ++i) {
            float4 v = *(const float4*)(S + (size_t)(r0 + rr + i) * ss + c0 + cc);
            T[rr + i][cc + 0] = v.x; T[rr + i][cc + 1] = v.y;
            T[rr + i][cc + 2] = v.z; T[rr + i][cc + 3] = v.w;
        }
    }
    __syncthreads();
    int cr = t >> 2, rc = (t & 3) * 16;
    u32 o[8];
#pragma unroll
    for (int j = 0; j < 8; ++j)
        o[j] = packh(T[rc + 2 * j][cr], T[rc + 2 * j + 1][cr]);
    u16* d = D + (size_t)(c0 + cr) * ds + r0 + rc;
    *(uint4*)(d)     = make_uint4(o[0], o[1], o[2], o[3]);
    *(uint4*)(d + 8) = make_uint4(o[4], o[5], o[6], o[7]);
}

__global__ __launch_bounds__(256) void tconv(
    const float* __restrict__ src, u16* __restrict__ dst,
    int ss, int ds, size_t sbo, size_t dbo)
{
    tconv_body(src + (size_t)blockIdx.z * sbo, dst + (size_t)blockIdx.z * dbo,
               ss, ds, blockIdx.x * 64, blockIdx.y * 64, threadIdx.x);
}

__global__ __launch_bounds__(256) void wo_convert(
    const float* __restrict__ Wo, u16* __restrict__ WoT)
{
    tconv_body(Wo, WoT, DMODEL, DMODEL, blockIdx.y * 64, blockIdx.x * 64, threadIdx.x);
}

// ---------------------------------------------------------------------------
// tconv_all (R14): all 5 prep transposes in one launch. Flat 8960 blocks:
//  [0,256)     We  -> WeT   | [256,512)   Wf -> WfT
//  [512,4608)  K   -> KT    | [4608,8704) V  -> VT
//  [8704,8960) Wo  -> WoT
// ---------------------------------------------------------------------------
__global__ __launch_bounds__(256) void tconv_all(
    const float* __restrict__ We, const float* __restrict__ Wf,
    const float* __restrict__ K,  const float* __restrict__ V,
    const float* __restrict__ Wo,
    u16* __restrict__ WeT, u16* __restrict__ WfT,
    u16* __restrict__ KT,  u16* __restrict__ VT, u16* __restrict__ WoT)
{
    const int id = blockIdx.x;
    const float* S; u16* D; int ss, ds, r0, c0;
    if (id < 512) {                       // We / Wf : [4096][256] -> [256][4096]
        int j = id & 255;
        S  = (id < 256) ? We : Wf;
        D  = (id < 256) ? WeT : WfT;
        ss = LK; ds = SEQ;
        r0 = (j & 63) * 64; c0 = (j >> 6) * 64;
    } else if (id < 8704) {               // K / V : [4096][1024] -> [1024][4096] per b
        int j  = id - 512;
        int isV = j >= 4096; if (isV) j -= 4096;
        int bz = j >> 10, rem = j & 1023;
        S  = (isV ? V : K) + (size_t)bz * SEQ * DMODEL;
        D  = (isV ? VT : KT) + (size_t)bz * DMODEL * SEQ;
        ss = DMODEL; ds = SEQ;
        r0 = (rem & 63) * 64; c0 = (rem >> 6) * 64;
    } else {                              // Wo : [1024][1024] -> [1024][1024]^T
        int j = id - 8704;
        S = Wo; D = WoT; ss = DMODEL; ds = DMODEL;
        r0 = (j & 15) * 64; c0 = (j >> 4) * 64;
    }
    tconv_body(S, D, ss, ds, r0, c0, threadIdx.x);
}

// ---------------------------------------------------------------------------
// proj_gemm / proj_both (R11/R12-proven, fallback paths): batched TN GEMM.
// ---------------------------------------------------------------------------
#define PROJ_BODY(Ab, Bb, bias, Cb, bias_on_row, c_row_stride, c0, r0)          \
    const int t  = threadIdx.x;                                                 \
    const int lane = t & 63;                                                    \
    const int w  = t >> 6;                                                      \
    const int wr = w >> 1, wc = w & 1;                                          \
    const int q  = lane >> 4, c = lane & 15;                                    \
    __shared__ u16 As[2][128 * 64];                                             \
    __shared__ u16 Bs[2][128 * 64];                                             \
    auto stage = [&](int buf, int kk) {                                         \
        _Pragma("unroll")                                                       \
        for (int i = 0; i < 4; ++i) {                                           \
            int li  = i * 256 + t;                                              \
            int row = li >> 3;                                                  \
            int c8  = (li & 7) ^ (row & 7);                                     \
            gl2lds16(Ab + (size_t)(r0 + row) * SEQ + kk + c8 * 8, &As[buf][(size_t)li * 8]); \
            gl2lds16(Bb + (size_t)(c0 + row) * SEQ + kk + c8 * 8, &Bs[buf][(size_t)li * 8]); \
        }                                                                       \
    };                                                                          \
    f32x4 acc[4][4];                                                            \
    _Pragma("unroll")                                                           \
    for (int m = 0; m < 4; ++m)                                                 \
        _Pragma("unroll")                                                       \
        for (int n = 0; n < 4; ++n) acc[m][n] = (f32x4){0.f, 0.f, 0.f, 0.f};    \
    stage(0, 0);                                                                \
    __syncthreads();                                                            \
    int cur = 0;                                                                \
    for (int k0 = 0; k0 < SEQ; k0 += 64) {                                      \
        if (k0 + 64 < SEQ) stage(cur ^ 1, k0 + 64);                             \
        _Pragma("unroll")                                                       \
        for (int s = 0; s < 2; ++s) {                                           \
            f16x8 af[4], bf[4];                                                 \
            _Pragma("unroll")                                                   \
            for (int m = 0; m < 4; ++m) {                                       \
                int row = wr * 64 + m * 16 + c;                                 \
                int c8  = (s * 4 + q) ^ (row & 7);                              \
                af[m] = *(const f16x8*)&As[cur][row * 64 + c8 * 8];             \
            }                                                                   \
            _Pragma("unroll")                                                   \
            for (int n = 0; n < 4; ++n) {                                       \
                int row = wc * 64 + n * 16 + c;                                 \
                int c8  = (s * 4 + q) ^ (row & 7);                              \
                bf[n] = *(const f16x8*)&Bs[cur][row * 64 + c8 * 8];             \
            }                                                                   \
            _Pragma("unroll")                                                   \
            for (int m = 0; m < 4; ++m)                                         \
                _Pragma("unroll")                                               \
                for (int n = 0; n < 4; ++n)                                     \
                    acc[m][n] = __builtin_amdgcn_mfma_f32_16x16x32_f16(af[m], bf[n], acc[m][n], 0, 0, 0); \
        }                                                                       \
        __syncthreads();                                                        \
        cur ^= 1;                                                               \
    }                                                                           \
    if (bias_on_row) {                                                          \
        _Pragma("unroll")                                                       \
        for (int m = 0; m < 4; ++m) {                                           \
            int rowb = r0 + wr * 64 + m * 16 + q * 4;                           \
            _Pragma("unroll")                                                   \
            for (int r = 0; r < 4; ++r) {                                       \
                float bv = bias[rowb + r];                                      \
                u16* dst = Cb + (size_t)(rowb + r) * c_row_stride + c0 + wc * 64 + c; \
                _Pragma("unroll")                                               \
                for (int n = 0; n < 4; ++n) dst[n * 16] = f2h(acc[m][n][r] + bv); \
            }                                                                   \
        }                                                                       \
    } else {                                                                    \
        float bv[4];                                                            \
        _Pragma("unroll")                                                       \
        for (int n = 0; n < 4; ++n) bv[n] = bias[c0 + wc * 64 + n * 16 + c];    \
        _Pragma("unroll")                                                       \
        for (int m = 0; m < 4; ++m) {                                           \
            int rowb = r0 + wr * 64 + m * 16 + q * 4;                           \
            _Pragma("unroll")                                                   \
            for (int r = 0; r < 4; ++r) {                                       \
                u16* dst = Cb + (size_t)(rowb + r) * c_row_stride + c0 + wc * 64 + c; \
                _Pragma("unroll")                                               \
                for (int n = 0; n < 4; ++n) dst[n * 16] = f2h(acc[m][n][r] + bv[n]); \
            }                                                                   \
        }                                                                       \
    }

__global__ __launch_bounds__(256) void proj_gemm(
    const u16* __restrict__ A, const u16* __restrict__ B,
    const float* __restrict__ bias, u16* __restrict__ Cout,
    int bias_on_row, size_t a_batch, size_t b_batch,
    int c_row_stride, size_t c_batch)
{
    const u16* Ab = A + (size_t)blockIdx.z * a_batch;
    const u16* Bb = B + (size_t)blockIdx.z * b_batch;
    u16* Cb       = Cout + (size_t)blockIdx.z * c_batch;
    const int c0 = blockIdx.x * 128;
    const int r0 = blockIdx.y * 128;
    PROJ_BODY(Ab, Bb, bias, Cb, bias_on_row, c_row_stride, c0, r0)
}

__global__ __launch_bounds__(256) void proj_both(
    const u16* __restrict__ WeT, const u16* __restrict__ WfT,
    const u16* __restrict__ KT,  const u16* __restrict__ VT,
    const float* __restrict__ be, const float* __restrict__ bfp,
    u16* __restrict__ KpF, u16* __restrict__ VpF)
{
    const int id = blockIdx.x;
    const u16 *Ab, *Bb; const float* bias; u16* Cb;
    int bias_on_row, c_row_stride, c0, r0;
    if (id < 64) {              // K-proj: C[lk][dm] = WeT @ KT[b]^T + be[lk]
        int b = id >> 4, s = id & 15;
        c0 = (s & 7) * 128; r0 = (s >> 3) * 128;
        Ab = WeT; Bb = KT + (size_t)b * DMODEL * SEQ;
        bias = be; bias_on_row = 1;
        Cb = KpF + (size_t)b * LK * DMODEL; c_row_stride = DMODEL;
    } else {                    // V-proj: C[dm][lk] = VT[b] @ WfT^T + bf[lk]
        int j = id - 64, b = j >> 4, s = j & 15;
        c0 = (s & 1) * 128; r0 = (s >> 1) * 128;
        Ab = VT + (size_t)b * DMODEL * SEQ; Bb = WfT;
        bias = bfp; bias_on_row = 0;
        Cb = VpF + (size_t)b * DMODEL * LK; c_row_stride = LK;
    }
    PROJ_BODY(Ab, Bb, bias, Cb, bias_on_row, c_row_stride, c0, r0)
}

// ---------------------------------------------------------------------------
// proj_split (R14): split-K variant. 512 blocks = {sk 0..3} x {proven 128-tile
// decode}. Each does K in [sk*1024, sk*1024+1024) with the identical staging/
// compute loop, storing f32 partials (no bias).
// ---------------------------------------------------------------------------
__global__ __launch_bounds__(256) void proj_split(
    const u16* __restrict__ WeT, const u16* __restrict__ WfT,
    const u16* __restrict__ KT,  const u16* __restrict__ VT,
    float* __restrict__ PPK, float* __restrict__ PPV)
{
    const int sk = blockIdx.x >> 7;
    const int id = blockIdx.x & 127;
    const u16 *Ab, *Bb; float* Pout;
    int crs, c0, r0;
    if (id < 64) {              // K-proj partial [sk][b][lk][dm]
        int b = id >> 4, s = id & 15;
        c0 = (s & 7) * 128; r0 = (s >> 3) * 128;
        Ab = WeT; Bb = KT + (size_t)b * DMODEL * SEQ;
        Pout = PPK + ((size_t)sk * BB + b) * (LK * DMODEL); crs = DMODEL;
    } else {                    // V-proj partial [sk][b][dm][lk]
        int j = id - 64, b = j >> 4, s = j & 15;
        c0 = (s & 1) * 128; r0 = (s >> 1) * 128;
        Ab = VT + (size_t)b * DMODEL * SEQ; Bb = WfT;
        Pout = PPV + ((size_t)sk * BB + b) * (DMODEL * LK); crs = LK;
    }
    const int kbeg = sk * (SEQ / SPLITK), kend = kbeg + SEQ / SPLITK;

    const int t  = threadIdx.x;
    const int lane = t & 63;
    const int w  = t >> 6;
    const int wr = w >> 1, wc = w & 1;
    const int q  = lane >> 4, c = lane & 15;
    __shared__ u16 As[2][128 * 64];
    __shared__ u16 Bs[2][128 * 64];
    auto stage = [&](int buf, int kk) {
#pragma unroll
        for (int i = 0; i < 4; ++i) {
            int li  = i * 256 + t;
            int row = li >> 3;
            int c8  = (li & 7) ^ (row & 7);
            gl2lds16(Ab + (size_t)(r0 + row) * SEQ + kk + c8 * 8, &As[buf][(size_t)li * 8]);
            gl2lds16(Bb + (size_t)(c0 + row) * SEQ + kk + c8 * 8, &Bs[buf][(size_t)li * 8]);
        }
    };
    f32x4 acc[4][4];
#pragma unroll
    for (int m = 0; m < 4; ++m)
#pragma unroll
        for (int n = 0; n < 4; ++n) acc[m][n] = (f32x4){0.f, 0.f, 0.f, 0.f};
    stage(0, kbeg);
    __syncthreads();
    int cur = 0;
    for (int k0 = kbeg; k0 < kend; k0 += 64) {
        if (k0 + 64 < kend) stage(cur ^ 1, k0 + 64);
#pragma unroll
        for (int s = 0; s < 2; ++s) {
            f16x8 af[4], bf[4];
#pragma unroll
            for (int m = 0; m < 4; ++m) {
                int row = wr * 64 + m * 16 + c;
                int c8  = (s * 4 + q) ^ (row & 7);
                af[m] = *(const f16x8*)&As[cur][row * 64 + c8 * 8];
            }
#pragma unroll
            for (int n = 0; n < 4; ++n) {
                int row = wc * 64 + n * 16 + c;
                int c8  = (s * 4 + q) ^ (row & 7);
                bf[n] = *(const f16x8*)&Bs[cur][row * 64 + c8 * 8];
            }
#pragma unroll
            for (int m = 0; m < 4; ++m)
#pragma unroll
                for (int n = 0; n < 4; ++n)
                    acc[m][n] = __builtin_amdgcn_mfma_f32_16x16x32_f16(af[m], bf[n], acc[m][n], 0, 0, 0);
        }
        __syncthreads();
        cur ^= 1;
    }
    // f32 partial epilogue (no bias)
#pragma unroll
    for (int m = 0; m < 4; ++m) {
        int rowb = r0 + wr * 64 + m * 16 + q * 4;
#pragma unroll
        for (int r = 0; r < 4; ++r) {
            float* dst = Pout + (size_t)(rowb + r) * crs + c0 + wc * 64 + c;
#pragma unroll
            for (int n = 0; n < 4; ++n) dst[n * 16] = acc[m][n][r];
        }
    }
}

// ---------------------------------------------------------------------------
// proj_reduce (R14): sum SPLITK f32 partials + bias -> f16. grid (1024, 2).
// y=0: KpF[b][lk][dm], bias be[lk]=flat>>10 & 255 (same for a float4).
// y=1: VpF[b][dm][lk], bias bf[lk]=flat&255 (float4 of consecutive lk).
// ---------------------------------------------------------------------------
__global__ __launch_bounds__(256) void proj_reduce(
    const float* __restrict__ PPK, const float* __restrict__ PPV,
    const float* __restrict__ be,  const float* __restrict__ bfp,
    u16* __restrict__ KpF, u16* __restrict__ VpF)
{
    const int isV = blockIdx.y;
    const float* P    = isV ? PPV : PPK;
    const float* bias = isV ? bfp : be;
    u16* Out          = isV ? VpF : KpF;
    const size_t flat = ((size_t)blockIdx.x * 256 + threadIdx.x) * 4;  // elem idx
    const size_t skstride = (size_t)BB * LK * DMODEL;                  // floats
    float4 a = *(const float4*)(P + flat);
#pragma unroll
    for (int sk = 1; sk < SPLITK; ++sk) {
        float4 p = *(const float4*)(P + (size_t)sk * skstride + flat);
        a.x += p.x; a.y += p.y; a.z += p.z; a.w += p.w;
    }
    if (!isV) {
        float bv = bias[(flat >> 10) & 255];
        a.x += bv; a.y += bv; a.z += bv; a.w += bv;
    } else {
        float4 bv = *(const float4*)(bias + (flat & 255));
        a.x += bv.x; a.y += bv.y; a.z += bv.z; a.w += bv.w;
    }
    uint2 o = make_uint2(packh(a.x, a.y), packh(a.z, a.w));
    *(uint2*)(Out + flat) = o;
}

// ---------------------------------------------------------------------------
// Kernel 2 (R13-proven + R14 XCD swizzle): persistent-K/V fused attn.
// Grid 256 blocks (flat-decoded), 512 threads. Each XCD owns 8 whole (b,h).
// ---------------------------------------------------------------------------
__global__ __launch_bounds__(512) void attn_mfma(
    const float* __restrict__ Qin, const u16* __restrict__ KpF,
    const u16* __restrict__ VpF,   u16* __restrict__ AO)
{
    // bijective XCD swizzle: 256 blocks, xcd = lin%8 gets tids [xcd*32,+32)
    const int lin = blockIdx.x + blockIdx.y * gridDim.x;
    const int tid = (lin & 7) * 32 + (lin >> 3);
    const int bh = tid >> 2, b = bh >> 4, h = bh & 15;
    const int n0 = (tid & 3) * 1024;
    const int t  = threadIdx.x;
    const int w    = t >> 6;          // wave 0..7
    const int lane = t & 63;
    const int q    = lane >> 4;       // quad 0..3
    const int c    = lane & 15;

    __shared__ u16 Kl[16384];         // K [256][64], chunk ^ (row&7)
    __shared__ u16 Vl[16384];         // V [64][256], low-3 chunk bits ^ (row&7)
    __shared__ u16 Pl[128 * 264];     // P / out bounce, wave-local rows

    const u16* kbase = KpF + (size_t)b * LK * DMODEL + h * DK;
#pragma unroll
    for (int i = 0; i < 4; ++i) {
        int li = i * 512 + t;
        int row = li >> 3, ch = li & 7;
        int chs = ch ^ (row & 7);
        gl2lds16(kbase + (size_t)row * DMODEL + chs * 8, Kl + (size_t)li * 8);
    }
    const u16* vbase = VpF + ((size_t)b * DMODEL + h * DK) * LK;
#pragma unroll
    for (int i = 0; i < 4; ++i) {
        int li = i * 512 + t;
        int row = li >> 5, ch = li & 31;
        int chs = (ch & 24) | ((ch & 7) ^ (row & 7));
        gl2lds16(vbase + (size_t)row * LK + chs * 8, Vl + (size_t)li * 8);
    }
    __syncthreads();   // ONLY barrier

    const float* qbase = Qin + ((size_t)b * SEQ + n0 + w * 16 + c) * DMODEL + h * DK;
    const float4* qp0 = (const float4*)qbase;
    float4 q0 = qp0[2 * q], q1 = qp0[2 * q + 1];
    float4 q2 = qp0[8 + 2 * q], q3 = qp0[8 + 2 * q + 1];

    for (int p = 0; p < 8; ++p) {
        f16x8 a0 = pack8h(q0, q1);
        f16x8 a1 = pack8h(q2, q3);
        if (p < 7) {
            const float4* qp = (const float4*)(qbase + (size_t)(p + 1) * 128 * DMODEL);
            q0 = qp[2 * q]; q1 = qp[2 * q + 1];
            q2 = qp[8 + 2 * q]; q3 = qp[8 + 2 * q + 1];
        }

        f32x4 sc[16];
#pragma unroll
        for (int nt = 0; nt < 16; ++nt) sc[nt] = (f32x4){0.f, 0.f, 0.f, 0.f};
#pragma unroll
        for (int nt = 0; nt < 16; ++nt) {
            int ra = (nt * 16 + c) * 64;
            f16x8 b0 = *(const f16x8*)&Kl[ra + ((q ^ (c & 7)) * 8)];
            f16x8 b1 = *(const f16x8*)&Kl[ra + (((4 + q) ^ (c & 7)) * 8)];
            sc[nt] = __builtin_amdgcn_mfma_f32_16x16x32_f16(a0, b0, sc[nt], 0, 0, 0);
            sc[nt] = __builtin_amdgcn_mfma_f32_16x16x32_f16(a1, b1, sc[nt], 0, 0, 0);
        }

        float mx[4] = {-1e30f, -1e30f, -1e30f, -1e30f};
#pragma unroll
        for (int nt = 0; nt < 16; ++nt) {
            sc[nt] *= 0.125f;   // 1/sqrt(DK)
#pragma unroll
            for (int r = 0; r < 4; ++r) mx[r] = fmaxf(mx[r], sc[nt][r]);
        }
#pragma unroll
        for (int d = 1; d < 16; d <<= 1)
#pragma unroll
            for (int r = 0; r < 4; ++r) mx[r] = fmaxf(mx[r], __shfl_xor(mx[r], d, 64));

        float sm[4] = {0.f, 0.f, 0.f, 0.f};
#pragma unroll
        for (int nt = 0; nt < 16; ++nt)
#pragma unroll
            for (int r = 0; r < 4; ++r) {
                float e = __expf(sc[nt][r] - mx[r]);
                sc[nt][r] = e;
                sm[r] += e;
            }
#pragma unroll
        for (int d = 1; d < 16; d <<= 1)
#pragma unroll
            for (int r = 0; r < 4; ++r) sm[r] += __shfl_xor(sm[r], d, 64);
        float inv[4];
#pragma unroll
        for (int r = 0; r < 4; ++r) inv[r] = 1.0f / sm[r];

#pragma unroll
        for (int nt = 0; nt < 16; ++nt)
#pragma unroll
            for (int r = 0; r < 4; ++r)
                Pl[(w * 16 + q * 4 + r) * 264 + nt * 16 + c] = f2h(sc[nt][r] * inv[r]);

        f32x4 ov[4];
#pragma unroll
        for (int nt = 0; nt < 4; ++nt) ov[nt] = (f32x4){0.f, 0.f, 0.f, 0.f};
#pragma unroll
        for (int ks = 0; ks < 8; ++ks) {
            f16x8 pa = *(const f16x8*)&Pl[(w * 16 + c) * 264 + ks * 32 + q * 8];
#pragma unroll
            for (int nt = 0; nt < 4; ++nt) {
                int chunk = ks * 4 + q;
                int chs = (chunk & 24) | ((chunk & 7) ^ (c & 7));
                f16x8 vf = *(const f16x8*)&Vl[(nt * 16 + c) * 256 + chs * 8];
                ov[nt] = __builtin_amdgcn_mfma_f32_16x16x32_f16(pa, vf, ov[nt], 0, 0, 0);
            }
        }

#pragma unroll
        for (int nt = 0; nt < 4; ++nt)
#pragma unroll
            for (int r = 0; r < 4; ++r)
                Pl[(w * 16 + q * 4 + r) * 264 + nt * 16 + c] = f2h(ov[nt][r]);

#pragma unroll
        for (int ps = 0; ps < 2; ++ps) {
            int lr  = w * 16 + ps * 8 + (lane >> 3);
            int col = (lane & 7) * 8;
            uint4 vv = *(uint4*)&Pl[lr * 264 + col];
            *(uint4*)(AO + ((size_t)b * SEQ + n0 + p * 128 + lr) * DMODEL + h * DK + col) = vv;
        }
    }
}

// ---------------------------------------------------------------------------
// Kernel 3 (proven + R14 XCD swizzle): Out = AO(f16) @ WoT^T(f16) + bo.
// 1024 tiles; XCD xcd gets row-panels [xcd*16, xcd*16+16) x all 8 col-tiles.
// ---------------------------------------------------------------------------
#define OBM 128
#define OBN 128
#define OBK 64

__global__ __launch_bounds__(256) void out_gemm_mfma(
    const u16* __restrict__ AO, const u16* __restrict__ WoT,
    const float* __restrict__ bo, float* __restrict__ Out)
{
    const int lin = blockIdx.x + blockIdx.y * gridDim.x;   // 0..1023
    const int tid = (lin & 7) * 128 + (lin >> 3);
    const int r0 = (tid >> 3) * OBM;
    const int c0 = (tid & 7) * OBN;
    const int t  = threadIdx.x;
    const int lane = t & 63;
    const int w  = t >> 6;
    const int wr = w >> 1, wc = w & 1;
    const int q  = lane >> 4, c = lane & 15;

    __shared__ u16 As[OBM * OBK];
    __shared__ u16 Bs[OBN * OBK];

    f32x4 acc[4][4];
#pragma unroll
    for (int m = 0; m < 4; ++m)
#pragma unroll
        for (int n = 0; n < 4; ++n) acc[m][n] = (f32x4){0.f, 0.f, 0.f, 0.f};

    for (int k0 = 0; k0 < DMODEL; k0 += OBK) {
#pragma unroll
        for (int i = 0; i < 4; ++i) {
            int li  = i * 256 + t;
            int row = li >> 3;
            int c8  = (li & 7) ^ (row & 7);
            gl2lds16(AO  + (size_t)(r0 + row) * DMODEL + k0 + c8 * 8, (u16*)As + (size_t)li * 8);
            gl2lds16(WoT + (size_t)(c0 + row) * DMODEL + k0 + c8 * 8, (u16*)Bs + (size_t)li * 8);
        }
        __syncthreads();

#pragma unroll
        for (int s = 0; s < 2; ++s) {
            f16x8 af[4], bf[4];
#pragma unroll
            for (int m = 0; m < 4; ++m) {
                int row = wr * 64 + m * 16 + c;
                int c8  = (s * 4 + q) ^ (row & 7);
                af[m] = *(const f16x8*)&As[row * 64 + c8 * 8];
            }
#pragma unroll
            for (int n = 0; n < 4; ++n) {
                int row = wc * 64 + n * 16 + c;
                int c8  = (s * 4 + q) ^ (row & 7);
                bf[n] = *(const f16x8*)&Bs[row * 64 + c8 * 8];
            }
#pragma unroll
            for (int m = 0; m < 4; ++m)
#pragma unroll
                for (int n = 0; n < 4; ++n)
                    acc[m][n] = __builtin_amdgcn_mfma_f32_16x16x32_f16(af[m], bf[n], acc[m][n], 0, 0, 0);
        }
        __syncthreads();
    }

    float bv[4];
#pragma unroll
    for (int n = 0; n < 4; ++n) bv[n] = bo[c0 + wc * 64 + n * 16 + c];
#pragma unroll
    for (int m = 0; m < 4; ++m) {
        int rowb = r0 + wr * 64 + m * 16 + q * 4;
#pragma unroll
        for (int r = 0; r < 4; ++r) {
            float* dst = Out + (size_t)(rowb + r) * DMODEL + c0 + wc * 64 + c;
#pragma unroll
            for (int n = 0; n < 4; ++n) dst[n * 16] = acc[m][n][r] + bv[n];
        }
    }
}

// ---------------------------------------------------------------------------
extern "C" void kernel_launch(void* const* d_in, const int* in_sizes, int n_in,
                              void* d_out, int out_size, void* d_ws, size_t ws_size,
                              hipStream_t stream)
{
    const float* K   = (const float*)d_in[0];
    const float* Q   = (const float*)d_in[1];
    const float* V   = (const float*)d_in[2];
    const float* We  = (const float*)d_in[3];
    const float* be  = (const float*)d_in[4];
    const float* Wf  = (const float*)d_in[5];
    const float* bfp = (const float*)d_in[6];
    const float* Wo  = (const float*)d_in[7];
    const float* bo  = (const float*)d_in[8];
    float* Out = (float*)d_out;

    const size_t M1 = 1048576;                     // elems (2MB)
    const size_t TB = (size_t)BB * DMODEL * SEQ;   // elems (33.5MB)
    const size_t PFLOATS = (size_t)SPLITK * BB * LK * DMODEL;  // 4.19M floats
    const size_t NEED_SPLIT = (5 * M1 + 2 * TB) * 2 + 2 * PFLOATS * 4;  // ~111MB
    const size_t NEED_PAR   = 2 * (4 * M1 + 2 * TB);                     // ~75.5MB

    if (ws_size >= NEED_SPLIT) {
        // ---- R14 split-K layout (~111MB):
        //  KpF|VpF|WeT|WfT|WoT (5x2MB) | KT | VT (2x33.5MB) | PPK|PPV (2x16.8MB)
        u16* KpF = (u16*)d_ws;
        u16* VpF = KpF + M1;
        u16* WeT = VpF + M1;
        u16* WfT = WeT + M1;
        u16* WoT = WfT + M1;
        u16* KT  = WoT + M1;
        u16* VT  = KT + TB;
        float* PPK = (float*)(VT + TB);
        float* PPV = PPK + PFLOATS;
        u16* AO  = KT;                   // alias: KT dead after proj

        tconv_all<<<dim3(8960), 256, 0, stream>>>(We, Wf, K, V, Wo, WeT, WfT, KT, VT, WoT);
        proj_split<<<dim3(128 * SPLITK), 256, 0, stream>>>(WeT, WfT, KT, VT, PPK, PPV);
        proj_reduce<<<dim3(1024, 2), 256, 0, stream>>>(PPK, PPV, be, bfp, KpF, VpF);
        attn_mfma<<<dim3(4, BH), 512, 0, stream>>>(Q, KpF, VpF, AO);
        out_gemm_mfma<<<dim3(DMODEL / OBN, (BB * SEQ) / OBM), 256, 0, stream>>>(AO, WoT, bo, Out);
    } else if (ws_size >= NEED_PAR) {
        // ---- R13 parallel layout (75.5MB, proven) ----
        u16* KpF = (u16*)d_ws;
        u16* VpF = KpF + M1;
        u16* WeT = VpF + M1;
        u16* WfT = WeT + M1;
        u16* KT  = WfT + M1;
        u16* VT  = KT + TB;
        u16* AO  = KT;
        u16* WoT = WeT;

        tconv<<<dim3(SEQ / 64, LK / 64, 1), 256, 0, stream>>>(We, WeT, LK, SEQ, 0, 0);
        tconv<<<dim3(SEQ / 64, LK / 64, 1), 256, 0, stream>>>(Wf, WfT, LK, SEQ, 0, 0);
        tconv<<<dim3(SEQ / 64, DMODEL / 64, BB), 256, 0, stream>>>(
            K, KT, DMODEL, SEQ, (size_t)SEQ * DMODEL, (size_t)DMODEL * SEQ);
        tconv<<<dim3(SEQ / 64, DMODEL / 64, BB), 256, 0, stream>>>(
            V, VT, DMODEL, SEQ, (size_t)SEQ * DMODEL, (size_t)DMODEL * SEQ);
        proj_both<<<dim3(128), 256, 0, stream>>>(WeT, WfT, KT, VT, be, bfp, KpF, VpF);
        wo_convert<<<dim3(DMODEL / 64, DMODEL / 64), 256, 0, stream>>>(Wo, WoT);
        attn_mfma<<<dim3(4, BH), 512, 0, stream>>>(Q, KpF, VpF, AO);
        out_gemm_mfma<<<dim3(DMODEL / OBN, (BB * SEQ) / OBM), 256, 0, stream>>>(AO, WoT, bo, Out);
    } else {
        // ---- serial fallback == exact R11 layout (39.5MB proven) ----
        u16* KpF = (u16*)d_ws;
        u16* VpF = KpF + (size_t)BB * LK * DMODEL;
        u16* BIG = VpF + (size_t)BB * DMODEL * LK;
        u16* Wsm = BIG + (size_t)BB * SEQ * DMODEL;

        tconv<<<dim3(SEQ / 64, LK / 64, 1), 256, 0, stream>>>(We, Wsm, LK, SEQ, 0, 0);
        tconv<<<dim3(SEQ / 64, DMODEL / 64, BB), 256, 0, stream>>>(
            K, BIG, DMODEL, SEQ, (size_t)SEQ * DMODEL, (size_t)DMODEL * SEQ);
        proj_gemm<<<dim3(DMODEL / 128, LK / 128, BB), 256, 0, stream>>>(
            Wsm, BIG, be, KpF, 1, (size_t)0, (size_t)DMODEL * SEQ, DMODEL, (size_t)LK * DMODEL);
        tconv<<<dim3(SEQ / 64, LK / 64, 1), 256, 0, stream>>>(Wf, Wsm, LK, SEQ, 0, 0);
        tconv<<<dim3(SEQ / 64, DMODEL / 64, BB), 256, 0, stream>>>(
            V, BIG, DMODEL, SEQ, (size_t)SEQ * DMODEL, (size_t)DMODEL * SEQ);
        proj_gemm<<<dim3(LK / 128, DMODEL / 128, BB), 256, 0, stream>>>(
            BIG, Wsm, bfp, VpF, 0, (size_t)DMODEL * SEQ, (size_t)0, LK, (size_t)DMODEL * LK);
        wo_convert<<<dim3(DMODEL / 64, DMODEL / 64), 256, 0, stream>>>(Wo, Wsm);
        attn_mfma<<<dim3(4, BH), 512, 0, stream>>>(Q, KpF, VpF, BIG);
        out_gemm_mfma<<<dim3(DMODEL / OBN, (BB * SEQ) / OBM), 256, 0, stream>>>(BIG, Wsm, bo, Out);
    }
}